// Round 4
// baseline (1068.294 us; speedup 1.0000x reference)
//
#include <hip/hip_runtime.h>
#include <hip/hip_bf16.h>

#define NN 100000
#define NE 1600000
#define DD 128
#define GG 64
#define BN_EPS 1e-5f

typedef unsigned short u16;
using f32x4 = __attribute__((ext_vector_type(4))) float;
using s16x8 = __attribute__((ext_vector_type(8))) short;

constexpr int SCAN_B = 1024;
constexpr int NB = (NN + SCAN_B - 1) / SCAN_B;  // 98

__device__ __forceinline__ unsigned enc_f(float v) {
  unsigned u = __float_as_uint(v);
  return (u & 0x80000000u) ? ~u : (u | 0x80000000u);
}
__device__ __forceinline__ float dec_f(unsigned k) {
  unsigned u = (k & 0x80000000u) ? (k & 0x7FFFFFFFu) : ~k;
  return __uint_as_float(u);
}
__device__ __forceinline__ u16 f2b(float x) {
  __hip_bfloat16 h = __float2bfloat16(x);
  return *(u16*)&h;
}
__device__ __forceinline__ float b2f(u16 u) {
  unsigned v = ((unsigned)u) << 16;
  return __uint_as_float(v);
}
__device__ __forceinline__ float blo(unsigned v) { return __uint_as_float(v << 16); }
__device__ __forceinline__ float bhi(unsigned v) { return __uint_as_float(v & 0xFFFF0000u); }

// ---------------- init ----------------
__global__ void k_init(int* cursor, float* stats, unsigned* gemb_enc) {
  int i = blockIdx.x * blockDim.x + threadIdx.x;
  if (i < NN) cursor[i] = 0;
  if (i < 7*2*DD) stats[i] = 0.f;
  if (i < GG*DD) gemb_enc[i] = 0x007FFFFFu;  // enc(-inf)
}

// ---------------- CSR build, pass 1 ----------------
__global__ void k_fill1(const int* __restrict__ to, int* cursor, int* __restrict__ tmp_pos) {
  int e = blockIdx.x * blockDim.x + threadIdx.x;
  if (e >= NE) return;
  tmp_pos[e] = atomicAdd(&cursor[to[e]], 1);
}

// ---------------- scan over cursor(=deg) -> exclusive row_ptr ----------------
__global__ void k_scan1(const int* __restrict__ deg, int* row_ptr, int* bsum) {
  __shared__ int lds[SCAN_B];
  int t = threadIdx.x, i = blockIdx.x * SCAN_B + t;
  int v = (i < NN) ? deg[i] : 0;
  lds[t] = v;
  __syncthreads();
  for (int off = 1; off < SCAN_B; off <<= 1) {
    int add = (t >= off) ? lds[t - off] : 0;
    __syncthreads();
    lds[t] += add;
    __syncthreads();
  }
  if (i < NN) row_ptr[i] = lds[t] - v;
  if (t == SCAN_B - 1) bsum[blockIdx.x] = lds[t];
}

__global__ void k_scan2(const int* __restrict__ bsum, int* boff, int* row_ptr) {
  __shared__ int lds[128];
  int t = threadIdx.x;
  int v = (t < NB) ? bsum[t] : 0;
  lds[t] = v;
  __syncthreads();
  for (int off = 1; off < 128; off <<= 1) {
    int add = (t >= off) ? lds[t - off] : 0;
    __syncthreads();
    lds[t] += add;
    __syncthreads();
  }
  if (t < NB) boff[t] = lds[t] - v;
  if (t == 127) row_ptr[NN] = lds[127];
}

__global__ void k_scan3(int* row_ptr, const int* __restrict__ boff) {
  int i = blockIdx.x * blockDim.x + threadIdx.x;
  if (i >= NN) return;
  row_ptr[i] += boff[i >> 10];
}

// ---------------- CSR build, pass 2: scatter (no atomics) ----------------
__global__ void k_fill2(const int* __restrict__ from, const int* __restrict__ to,
                        const int* __restrict__ tmp_pos, const int* __restrict__ row_ptr,
                        int* __restrict__ csr_src, int* __restrict__ csr_eid) {
  int e = blockIdx.x * blockDim.x + threadIdx.x;
  if (e >= NE) return;
  int pos = row_ptr[to[e]] + tmp_pos[e];
  csr_src[pos] = from[e];
  csr_eid[pos] = e;
}

// ---------------- per-node raw edge-feature aggregation: 16 lanes/node ----------------
__global__ void k_node_ef(const float* __restrict__ ef, const int* __restrict__ row_ptr,
                          const int* __restrict__ csr_eid, float* __restrict__ agg4) {
  int grp = (blockIdx.x * 256 + threadIdx.x) >> 4;   // node
  if (grp >= NN) return;
  int l = threadIdx.x & 15;
  int s = row_ptr[grp], e = row_ptr[grp + 1];
  float a0 = 0.f, a1 = 0.f, a2 = 0.f;
  for (int i = s + l; i < e; i += 16) {
    int eid = csr_eid[i];
    a0 += ef[(size_t)eid * 3 + 0];
    a1 += ef[(size_t)eid * 3 + 1];
    a2 += ef[(size_t)eid * 3 + 2];
  }
#pragma unroll
  for (int off = 8; off; off >>= 1) {
    a0 += __shfl_down(a0, off, 16);
    a1 += __shfl_down(a1, off, 16);
    a2 += __shfl_down(a2, off, 16);
  }
  if (l == 0)
    ((float4*)agg4)[grp] = make_float4(a0, a1, a2, (float)(e - s));
}

// ---------------- weight prep ----------------
template<int MODE>
__device__ __forceinline__ void wprep_body(
    const float* __restrict__ W, const float* __restrict__ bias,
    const float* __restrict__ in_stats, const float* __restrict__ in_g,
    const float* __restrict__ in_b,
    const float* __restrict__ res_stats, const float* __restrict__ res_g,
    const float* __restrict__ res_b,
    u16* __restrict__ WT, float* __restrict__ biasP, float* __restrict__ rese) {
  __shared__ float s_s[DD], s_t[DD];
  int t = threadIdx.x;
  if (t < DD) {
    float s = 1.f, tt = 0.f;
    if (MODE == 1) {
      float mean = in_stats[t] * (1.f / NN);
      float var  = in_stats[DD + t] * (1.f / NN) - mean * mean;
      float rs = rsqrtf(var + BN_EPS);
      s = in_g[t] * rs;
      tt = in_b[t] - mean * s;
      float m2 = res_stats[t] * (1.f / NN);
      float v2 = res_stats[DD + t] * (1.f / NN) - m2 * m2;
      float r2 = rsqrtf(v2 + BN_EPS);
      float sc = res_g[t] * r2;
      rese[t] = sc;
      rese[DD + t] = res_b[t] - m2 * sc;
    }
    s_s[t] = s; s_t[t] = tt;
  }
  __syncthreads();
  for (int idx = t; idx < DD * DD; idx += 256) {
    int k = idx >> 7, n = idx & 127;
    WT[n * DD + k] = f2b(W[idx] * s_s[k]);
  }
  if (t < DD) {
    float acc = bias[t];
    if (MODE == 1)
      for (int k = 0; k < DD; ++k) acc += s_t[k] * W[k * DD + t];
    biasP[t] = acc;
  }
}

__global__ void k_wprep0(const float* __restrict__ w_n2l_w, const float* __restrict__ w_n2l_b,
                         const float* __restrict__ conv_w, const float* __restrict__ conv_b,
                         u16* wt0, float* bp0, u16* wt1, float* bp1,
                         u16* wt3, float* bp3, u16* wt5, float* bp5) {
  int blk = blockIdx.x;
  const float* W; const float* bias; u16* WT; float* biasP;
  if (blk == 0)      { W = w_n2l_w;              bias = w_n2l_b;          WT = wt0; biasP = bp0; }
  else if (blk == 1) { W = conv_w;               bias = conv_b;           WT = wt1; biasP = bp1; }
  else if (blk == 2) { W = conv_w + DD * DD;     bias = conv_b + DD;      WT = wt3; biasP = bp3; }
  else               { W = conv_w + 2 * DD * DD; bias = conv_b + 2 * DD;  WT = wt5; biasP = bp5; }
  wprep_body<0>(W, bias, nullptr, nullptr, nullptr, nullptr, nullptr, nullptr,
                WT, biasP, nullptr);
}

__global__ void k_wprep1(const float* __restrict__ W, const float* __restrict__ bias,
                         const float* __restrict__ in_stats, const float* __restrict__ in_g,
                         const float* __restrict__ in_b,
                         const float* __restrict__ res_stats, const float* __restrict__ res_g,
                         const float* __restrict__ res_b,
                         u16* WT, float* biasP, float* rese) {
  wprep_body<1>(W, bias, in_stats, in_g, in_b, res_stats, res_g, res_b, WT, biasP, rese);
}

// swizzled LDS byte address: granule XOR within 8-granule (128B) halves of a 256B row
__device__ __forceinline__ int swz_addr(int row_bytes, int xr, int g, int o) {
  return row_bytes + ((((g & 7) ^ xr) | (g & 8)) << 4) + o;
}

// ---------------- MFMA GEMM ----------------
// MODE 0: A = on-the-fly gather(affine(R)) via CSR; extra = e2n from agg4
// MODE 1: A = bf16 buffer via global_load_lds; extra = affine(resid)
// MODE 2: A = fp32 buffer with on-the-fly bf16 cvt; extra = e2n from agg4
template<int MODE>
__global__ __launch_bounds__(256, 2)
void k_gemm(const void* __restrict__ Ain, const u16* __restrict__ WT,
            const float* __restrict__ biasP, u16* __restrict__ out,
            float* __restrict__ stats_out,
            const int* __restrict__ row_ptr, const int* __restrict__ csr_src,
            const float* __restrict__ gstats, const float* __restrict__ gg,
            const float* __restrict__ gb,
            const float* __restrict__ rese, const u16* __restrict__ resid,
            const float4* __restrict__ agg4,
            const float* __restrict__ w_e2l, const float* __restrict__ b_e2l) {
  __shared__ __align__(16) u16 lds_a[128 * 128];   // 32 KB, swizzled
  __shared__ __align__(16) u16 lds_b[128 * 128];   // 32 KB, swizzled
  __shared__ float sstats[2 * DD];
  const int tid  = threadIdx.x;
  const int lane = tid & 63;
  const int wv   = tid >> 6;
  const int row0 = blockIdx.x * 128;

  if (tid < 2 * DD) sstats[tid] = 0.f;

  // ---- stage WT (all modes) and A (MODE 1) via global_load_lds ----
#pragma unroll
  for (int c = 0; c < 8; ++c) {
    int gidx = (wv * 8 + c) * 64 + lane;
    int row = gidx >> 4, gL = gidx & 15;
    int gS = (gL & 8) | ((gL & 7) ^ (row & 7));
    const u16* gsrcB = WT + (size_t)row * DD + gS * 8;
    u16* ldstB = lds_b + (size_t)(wv * 8 + c) * 512;
    __builtin_amdgcn_global_load_lds(
        (const __attribute__((address_space(1))) unsigned int*)gsrcB,
        (__attribute__((address_space(3))) unsigned int*)ldstB, 16, 0, 0);
    if (MODE == 1) {
      int arow = row0 + row; if (arow >= NN) arow = NN - 1;
      const u16* gsrcA = (const u16*)Ain + (size_t)arow * DD + gS * 8;
      u16* ldstA = lds_a + (size_t)(wv * 8 + c) * 512;
      __builtin_amdgcn_global_load_lds(
          (const __attribute__((address_space(1))) unsigned int*)gsrcA,
          (__attribute__((address_space(3))) unsigned int*)ldstA, 16, 0, 0);
    }
  }

  // ---- A staging by computation (MODE 0: gather, MODE 2: f32->bf16) ----
  if (MODE == 0) {
    // per-lane affine for dims d0=lane*2, d0+1
    const int d0 = lane * 2;
    float m0 = gstats[d0] * (1.f / NN), m1 = gstats[d0 + 1] * (1.f / NN);
    float v0 = gstats[DD + d0] * (1.f / NN) - m0 * m0;
    float v1 = gstats[DD + d0 + 1] * (1.f / NN) - m1 * m1;
    float sc0 = gg[d0] * rsqrtf(v0 + BN_EPS), sc1 = gg[d0 + 1] * rsqrtf(v1 + BN_EPS);
    float sh0 = gb[d0] - m0 * sc0, sh1 = gb[d0 + 1] - m1 * sc1;
    const unsigned* R1 = (const unsigned*)Ain;   // row = 64 uints (128 bf16)
    const int gLn = lane >> 2, oin = (lane & 3) * 4;
    for (int rr = 0; rr < 32; ++rr) {
      int r = wv * 32 + rr;
      int n = row0 + r; if (n >= NN) n = NN - 1;
      int s = row_ptr[n], e = row_ptr[n + 1];
      float a0 = 0.f, a1 = 0.f;
      int i = s;
      for (; i + 7 < e; i += 8) {
        int q0 = csr_src[i],     q1 = csr_src[i + 1], q2 = csr_src[i + 2], q3 = csr_src[i + 3];
        int q4 = csr_src[i + 4], q5 = csr_src[i + 5], q6 = csr_src[i + 6], q7 = csr_src[i + 7];
        unsigned w0 = R1[(size_t)q0 * 64 + lane], w1 = R1[(size_t)q1 * 64 + lane];
        unsigned w2 = R1[(size_t)q2 * 64 + lane], w3 = R1[(size_t)q3 * 64 + lane];
        unsigned w4 = R1[(size_t)q4 * 64 + lane], w5 = R1[(size_t)q5 * 64 + lane];
        unsigned w6 = R1[(size_t)q6 * 64 + lane], w7 = R1[(size_t)q7 * 64 + lane];
        a0 += blo(w0) + blo(w1) + blo(w2) + blo(w3) + blo(w4) + blo(w5) + blo(w6) + blo(w7);
        a1 += bhi(w0) + bhi(w1) + bhi(w2) + bhi(w3) + bhi(w4) + bhi(w5) + bhi(w6) + bhi(w7);
      }
      for (; i < e; ++i) {
        unsigned w = R1[(size_t)csr_src[i] * 64 + lane];
        a0 += blo(w); a1 += bhi(w);
      }
      float dgf = (float)(e - s);
      float r0 = sc0 * a0 + sh0 * dgf;
      float r1 = sc1 * a1 + sh1 * dgf;
      unsigned pk = (unsigned)f2b(r0) | ((unsigned)f2b(r1) << 16);
      int gS = (gLn & 8) | ((gLn & 7) ^ (r & 7));
      *(unsigned*)((char*)lds_a + r * 256 + gS * 16 + oin) = pk;
    }
  } else if (MODE == 2) {
    const float2* Af = (const float2*)Ain;       // row = 64 float2 (128 f32)
    const int gLn = lane >> 2, oin = (lane & 3) * 4;
    for (int rr = 0; rr < 32; ++rr) {
      int r = wv * 32 + rr;
      int n = row0 + r; if (n >= NN) n = NN - 1;
      float2 v = Af[(size_t)n * 64 + lane];
      unsigned pk = (unsigned)f2b(v.x) | ((unsigned)f2b(v.y) << 16);
      int gS = (gLn & 8) | ((gLn & 7) ^ (r & 7));
      *(unsigned*)((char*)lds_a + r * 256 + gS * 16 + oin) = pk;
    }
  }
  __syncthreads();

  const int colid = lane & 15;
  const int lgrp  = lane >> 4;
  const int rowbase = wv * 32;
  const int o = (lgrp & 1) * 8;

  s16x8 afr[2][4];
#pragma unroll
  for (int rf = 0; rf < 2; ++rf) {
    int r = rowbase + rf * 16 + colid;
    int rb = r << 8, xr = r & 7;
#pragma unroll
    for (int ks = 0; ks < 4; ++ks) {
      int g0 = ks * 4 + (lgrp >> 1);
      uint2 lo = *(const uint2*)((const char*)lds_a + swz_addr(rb, xr, g0, o));
      uint2 hi = *(const uint2*)((const char*)lds_a + swz_addr(rb, xr, g0 + 2, o));
      union { unsigned u[4]; s16x8 v; } pk;
      pk.u[0] = lo.x; pk.u[1] = lo.y; pk.u[2] = hi.x; pk.u[3] = hi.y;
      afr[rf][ks] = pk.v;
    }
  }

  float4 ev[2][4];
  if (MODE != 1) {
#pragma unroll
    for (int rf = 0; rf < 2; ++rf)
#pragma unroll
      for (int q = 0; q < 4; ++q) {
        int r = row0 + rowbase + rf * 16 + lgrp * 4 + q;
        if (r >= NN) r = NN - 1;
        ev[rf][q] = agg4[r];
      }
  }

  for (int cf = 0; cf < 8; ++cf) {
    const int col = cf * 16 + colid;
    float bp = biasP[col];
    f32x4 acc0, acc1;
    if (MODE == 1) {
      float sc = rese[col], sh = rese[DD + col];
#pragma unroll
      for (int rf = 0; rf < 2; ++rf)
#pragma unroll
        for (int q = 0; q < 4; ++q) {
          int r = row0 + rowbase + rf * 16 + lgrp * 4 + q;
          int rc = r < NN ? r : NN - 1;
          float v = bp + sc * b2f(resid[(size_t)rc * DD + col]) + sh;
          if (rf == 0) acc0[q] = v; else acc1[q] = v;
        }
    } else {
#pragma unroll
      for (int rf = 0; rf < 2; ++rf)
#pragma unroll
        for (int q = 0; q < 4; ++q) {
          float4 e4 = ev[rf][q];
          float v = bp + e4.x * w_e2l[col] + e4.y * w_e2l[DD + col]
                       + e4.z * w_e2l[2 * DD + col] + e4.w * b_e2l[col];
          if (rf == 0) acc0[q] = v; else acc1[q] = v;
        }
    }
    {
      int nb = col << 8, xn = col & 7;
#pragma unroll
      for (int ks = 0; ks < 4; ++ks) {
        int g0 = ks * 4 + (lgrp >> 1);
        uint2 lo = *(const uint2*)((const char*)lds_b + swz_addr(nb, xn, g0, o));
        uint2 hi = *(const uint2*)((const char*)lds_b + swz_addr(nb, xn, g0 + 2, o));
        union { unsigned u[4]; s16x8 v; } pk;
        pk.u[0] = lo.x; pk.u[1] = lo.y; pk.u[2] = hi.x; pk.u[3] = hi.y;
        acc0 = __builtin_amdgcn_mfma_f32_16x16x32_bf16(afr[0][ks], pk.v, acc0, 0, 0, 0);
        acc1 = __builtin_amdgcn_mfma_f32_16x16x32_bf16(afr[1][ks], pk.v, acc1, 0, 0, 0);
      }
    }
    float s = 0.f, s2 = 0.f;
#pragma unroll
    for (int rf = 0; rf < 2; ++rf)
#pragma unroll
      for (int q = 0; q < 4; ++q) {
        int r = row0 + rowbase + rf * 16 + lgrp * 4 + q;
        float v = fmaxf(rf == 0 ? acc0[q] : acc1[q], 0.f);
        if (r < NN) {
          out[(size_t)r * DD + col] = f2b(v);
          s += v; s2 += v * v;
        }
      }
    s  += __shfl_xor(s, 16);  s  += __shfl_xor(s, 32);
    s2 += __shfl_xor(s2, 16); s2 += __shfl_xor(s2, 32);
    if (lgrp == 0) {
      atomicAdd(&sstats[col], s);
      atomicAdd(&sstats[DD + col], s2);
    }
  }
  __syncthreads();
  if (tid < 2 * DD) atomicAdd(&stats_out[tid], sstats[tid]);
}

// ---------------- segment max (bf16 input) ----------------
__global__ void k_segmax(const u16* __restrict__ R, const int* __restrict__ g_idx,
                         unsigned* __restrict__ gemb_enc,
                         const float* __restrict__ stats, const float* __restrict__ g,
                         const float* __restrict__ b) {
  int t = blockIdx.x * blockDim.x + threadIdx.x;
  int d = t & (DD - 1);
  int chunk = t >> 7;
  int n0 = chunk * 8;
  if (n0 >= NN) return;
  float mean = stats[d] * (1.f / NN);
  float var  = stats[DD + d] * (1.f / NN) - mean * mean;
  float rs = rsqrtf(var + BN_EPS);
  float scale = g[d] * rs;
  float shift = b[d] - mean * scale;
  int cur = -1; float run = 0.f;
  int nend = n0 + 8; if (nend > NN) nend = NN;
  for (int n = n0; n < nend; ++n) {
    float v = scale * b2f(R[(size_t)n * DD + d]) + shift;
    int gi = g_idx[n];
    if (gi != cur) {
      if (cur >= 0) atomicMax(&gemb_enc[cur * DD + d], enc_f(run));
      cur = gi; run = v;
    } else {
      run = fmaxf(run, v);
    }
  }
  if (cur >= 0) atomicMax(&gemb_enc[cur * DD + d], enc_f(run));
}

// ---------------- readout ----------------
__global__ void k_readout(const unsigned* __restrict__ gemb,
                          const float* __restrict__ W, const float* __restrict__ b,
                          float* __restrict__ out) {
  __shared__ float row[DD];
  int g = blockIdx.x, t = threadIdx.x;
  row[t] = dec_f(gemb[g * DD + t]);
  __syncthreads();
  float acc = b[t];
  for (int d = 0; d < DD; ++d) acc += row[d] * W[d * DD + t];
  out[g * DD + t] = fmaxf(acc, 0.f);
}

extern "C" void kernel_launch(void* const* d_in, const int* in_sizes, int n_in,
                              void* d_out, int out_size, void* d_ws, size_t ws_size,
                              hipStream_t stream) {
  const float* node_feat = (const float*)d_in[0];
  const float* edge_feat = (const float*)d_in[1];
  const int*   efrom     = (const int*)d_in[2];
  const int*   eto       = (const int*)d_in[3];
  const int*   g_idx     = (const int*)d_in[4];
  const float* w_n2l_w   = (const float*)d_in[6];
  const float* w_n2l_b   = (const float*)d_in[7];
  const float* w_e2l_w   = (const float*)d_in[8];   // [4][3][128]
  const float* w_e2l_b   = (const float*)d_in[9];   // [4][128]
  const float* conv_w    = (const float*)d_in[10];  // [3][128][128]
  const float* conv_b    = (const float*)d_in[11];
  const float* l2_w      = (const float*)d_in[12];
  const float* l2_b      = (const float*)d_in[13];
  const float* msg_bn_g  = (const float*)d_in[14];  // [4][128]
  const float* msg_bn_b  = (const float*)d_in[15];
  const float* hid_bn_g  = (const float*)d_in[16];  // [3][128]
  const float* hid_bn_b  = (const float*)d_in[17];
  const float* readout_w = (const float*)d_in[18];
  const float* readout_b = (const float*)d_in[19];
  float* out = (float*)d_out;
  (void)in_sizes; (void)n_in; (void)out_size; (void)ws_size;

  char* ws = (char*)d_ws;
  size_t off = 0;
  auto alloc = [&](size_t bytes) -> void* {
    void* p = ws + off; off += (bytes + 511) & ~(size_t)511; return p;
  };
  u16*      Pb0     = (u16*)alloc((size_t)NN * DD * 2);
  u16*      Pb1     = (u16*)alloc((size_t)NN * DD * 2);
  u16*      Pb2     = (u16*)alloc((size_t)NN * DD * 2);
  float*    agg4    = (float*)alloc((size_t)NN * 4 * 4);
  int*      cursor  = (int*)alloc((size_t)NN * 4);
  int*      row_ptr = (int*)alloc((size_t)(NN + 1) * 4);
  int*      tmp_pos = (int*)alloc((size_t)NE * 4);
  int*      csr_src = (int*)alloc((size_t)NE * 4);
  int*      csr_eid = (int*)alloc((size_t)NE * 4);
  int*      bsum    = (int*)alloc((size_t)NB * 4);
  int*      boff    = (int*)alloc((size_t)NB * 4);
  float*    stats   = (float*)alloc((size_t)7 * 2 * DD * 4);
  unsigned* gemb    = (unsigned*)alloc((size_t)GG * DD * 4);
  u16*      wt[7];
  float*    bp[7];
  float*    re[7];
  for (int i = 0; i < 7; ++i) {
    wt[i] = (u16*)alloc((size_t)DD * DD * 2);
    bp[i] = (float*)alloc((size_t)DD * 4);
    re[i] = (float*)alloc((size_t)2 * DD * 4);
  }

  k_init<<<(NN + 255) / 256, 256, 0, stream>>>(cursor, stats, gemb);
  k_fill1<<<(NE + 255) / 256, 256, 0, stream>>>(eto, cursor, tmp_pos);
  k_scan1<<<NB, SCAN_B, 0, stream>>>(cursor, row_ptr, bsum);
  k_scan2<<<1, 128, 0, stream>>>(bsum, boff, row_ptr);
  k_scan3<<<(NN + 255) / 256, 256, 0, stream>>>(row_ptr, boff);
  k_fill2<<<(NE + 255) / 256, 256, 0, stream>>>(efrom, eto, tmp_pos, row_ptr,
                                                csr_src, csr_eid);
  k_node_ef<<<(NN * 16 + 255) / 256, 256, 0, stream>>>(edge_feat, row_ptr, csr_eid,
                                                       agg4);
  k_wprep0<<<4, 256, 0, stream>>>(w_n2l_w, w_n2l_b, conv_w, conv_b,
                                  wt[0], bp[0], wt[1], bp[1], wt[3], bp[3], wt[5], bp[5]);

  float* stat_msg[4] = { stats + 0*256, stats + 1*256, stats + 2*256, stats + 3*256 };
  float* stat_hid[3] = { stats + 4*256, stats + 5*256, stats + 6*256 };
  const int GEMM_GRID = (NN + 127) / 128;  // 782

  // GEMM0 (MODE 2): Pb0 = relu(bf16(node_feat) @ w_n2l + b + e2n0); stats -> msg[0]
  k_gemm<2><<<GEMM_GRID, 256, 0, stream>>>(node_feat, wt[0], bp[0], Pb0, stat_msg[0],
      nullptr, nullptr, nullptr, nullptr, nullptr, nullptr, nullptr,
      (const float4*)agg4, w_e2l_w + 0 * 3 * DD, w_e2l_b + 0 * DD);

  u16* R = Pb0; u16* other = Pb1;
  for (int lv = 0; lv < 3; ++lv) {
    int wc = 1 + 2 * lv, wl = 2 + 2 * lv;
    // fused gather+conv (MODE 0): Pb2 = relu(affine_msg[lv](seg(R[from])) @ conv_w[lv]
    //                                        + conv_b + e2n[lv+1]); stats -> hid[lv]
    k_gemm<0><<<GEMM_GRID, 256, 0, stream>>>(R, wt[wc], bp[wc], Pb2, stat_hid[lv],
        row_ptr, csr_src, stat_msg[lv], msg_bn_g + lv * DD, msg_bn_b + lv * DD,
        nullptr, nullptr, (const float4*)agg4,
        w_e2l_w + (size_t)(lv + 1) * 3 * DD, w_e2l_b + (lv + 1) * DD);
    // l2 (MODE 1): other = relu(norm_hid(Pb2) @ l2_w[lv] + l2_b + affine_msg[lv](R))
    k_wprep1<<<1, 256, 0, stream>>>(l2_w + (size_t)lv * DD * DD, l2_b + lv * DD,
        stat_hid[lv], hid_bn_g + lv * DD, hid_bn_b + lv * DD,
        stat_msg[lv], msg_bn_g + lv * DD, msg_bn_b + lv * DD, wt[wl], bp[wl], re[wl]);
    k_gemm<1><<<GEMM_GRID, 256, 0, stream>>>(Pb2, wt[wl], bp[wl], other, stat_msg[lv + 1],
        nullptr, nullptr, nullptr, nullptr, nullptr,
        re[wl], R, nullptr, nullptr, nullptr);
    u16* t = R; R = other; other = t;
  }

  k_segmax<<<(NN / 8) * DD / 256, 256, 0, stream>>>(
      R, g_idx, gemb, stat_msg[3], msg_bn_g + 3 * DD, msg_bn_b + 3 * DD);
  k_readout<<<GG, DD, 0, stream>>>(gemb, readout_w, readout_b, out);
}

// Round 5
// 824.315 us; speedup vs baseline: 1.2960x; 1.2960x over previous
//
#include <hip/hip_runtime.h>
#include <hip/hip_bf16.h>

#define NN 100000
#define NE 1600000
#define DD 128
#define GG 64
#define BN_EPS 1e-5f

typedef unsigned short u16;
using f32x4 = __attribute__((ext_vector_type(4))) float;
using s16x8 = __attribute__((ext_vector_type(8))) short;

constexpr int SCAN_B = 1024;
constexpr int NB = (NN + SCAN_B - 1) / SCAN_B;  // 98

__device__ __forceinline__ unsigned enc_f(float v) {
  unsigned u = __float_as_uint(v);
  return (u & 0x80000000u) ? ~u : (u | 0x80000000u);
}
__device__ __forceinline__ float dec_f(unsigned k) {
  unsigned u = (k & 0x80000000u) ? (k & 0x7FFFFFFFu) : ~k;
  return __uint_as_float(u);
}
__device__ __forceinline__ u16 f2b(float x) {
  __hip_bfloat16 h = __float2bfloat16(x);
  return *(u16*)&h;
}
__device__ __forceinline__ float b2f(u16 u) {
  unsigned v = ((unsigned)u) << 16;
  return __uint_as_float(v);
}
__device__ __forceinline__ float blo(unsigned v) { return __uint_as_float(v << 16); }
__device__ __forceinline__ float bhi(unsigned v) { return __uint_as_float(v & 0xFFFF0000u); }

// ---------------- init ----------------
__global__ void k_init(int* cursor, float* stats, unsigned* gemb_enc) {
  int i = blockIdx.x * blockDim.x + threadIdx.x;
  if (i < NN) cursor[i] = 0;
  if (i < 7*2*DD) stats[i] = 0.f;
  if (i < GG*DD) gemb_enc[i] = 0x007FFFFFu;  // enc(-inf)
}

// ---------------- CSR build, pass 1 ----------------
__global__ void k_fill1(const int* __restrict__ to, int* cursor, int* __restrict__ tmp_pos) {
  int e = blockIdx.x * blockDim.x + threadIdx.x;
  if (e >= NE) return;
  tmp_pos[e] = atomicAdd(&cursor[to[e]], 1);
}

// ---------------- scan over cursor(=deg) -> exclusive row_ptr ----------------
__global__ void k_scan1(const int* __restrict__ deg, int* row_ptr, int* bsum) {
  __shared__ int lds[SCAN_B];
  int t = threadIdx.x, i = blockIdx.x * SCAN_B + t;
  int v = (i < NN) ? deg[i] : 0;
  lds[t] = v;
  __syncthreads();
  for (int off = 1; off < SCAN_B; off <<= 1) {
    int add = (t >= off) ? lds[t - off] : 0;
    __syncthreads();
    lds[t] += add;
    __syncthreads();
  }
  if (i < NN) row_ptr[i] = lds[t] - v;
  if (t == SCAN_B - 1) bsum[blockIdx.x] = lds[t];
}

__global__ void k_scan2(const int* __restrict__ bsum, int* boff, int* row_ptr) {
  __shared__ int lds[128];
  int t = threadIdx.x;
  int v = (t < NB) ? bsum[t] : 0;
  lds[t] = v;
  __syncthreads();
  for (int off = 1; off < 128; off <<= 1) {
    int add = (t >= off) ? lds[t - off] : 0;
    __syncthreads();
    lds[t] += add;
    __syncthreads();
  }
  if (t < NB) boff[t] = lds[t] - v;
  if (t == 127) row_ptr[NN] = lds[127];
}

__global__ void k_scan3(int* row_ptr, const int* __restrict__ boff) {
  int i = blockIdx.x * blockDim.x + threadIdx.x;
  if (i >= NN) return;
  row_ptr[i] += boff[i >> 10];
}

// ---------------- CSR build, pass 2: scatter (no atomics) ----------------
__global__ void k_fill2(const int* __restrict__ from, const int* __restrict__ to,
                        const int* __restrict__ tmp_pos, const int* __restrict__ row_ptr,
                        int* __restrict__ csr_src, int* __restrict__ csr_eid) {
  int e = blockIdx.x * blockDim.x + threadIdx.x;
  if (e >= NE) return;
  int pos = row_ptr[to[e]] + tmp_pos[e];
  csr_src[pos] = from[e];
  csr_eid[pos] = e;
}

// ---------------- per-node raw edge-feature aggregation: 16 lanes/node ----------------
__global__ void k_node_ef(const float* __restrict__ ef, const int* __restrict__ row_ptr,
                          const int* __restrict__ csr_eid, float* __restrict__ agg4) {
  int grp = (blockIdx.x * 256 + threadIdx.x) >> 4;   // node
  if (grp >= NN) return;
  int l = threadIdx.x & 15;
  int s = row_ptr[grp], e = row_ptr[grp + 1];
  float a0 = 0.f, a1 = 0.f, a2 = 0.f;
  for (int i = s + l; i < e; i += 16) {
    int eid = csr_eid[i];
    a0 += ef[(size_t)eid * 3 + 0];
    a1 += ef[(size_t)eid * 3 + 1];
    a2 += ef[(size_t)eid * 3 + 2];
  }
#pragma unroll
  for (int off = 8; off; off >>= 1) {
    a0 += __shfl_down(a0, off, 16);
    a1 += __shfl_down(a1, off, 16);
    a2 += __shfl_down(a2, off, 16);
  }
  if (l == 0)
    ((float4*)agg4)[grp] = make_float4(a0, a1, a2, (float)(e - s));
}

// ---------------- neighbor gather: wave per node, 2 dims/lane, 8-deep unroll ----------------
__global__ __launch_bounds__(256)
void k_gather(const u16* __restrict__ R, u16* __restrict__ out,
              const int* __restrict__ row_ptr, const int* __restrict__ csr_src,
              const float* __restrict__ stats, const float* __restrict__ g,
              const float* __restrict__ b) {
  const int wid = (blockIdx.x * 256 + threadIdx.x) >> 6;   // node
  if (wid >= NN) return;
  const int lane = threadIdx.x & 63;
  const int s = row_ptr[wid], e = row_ptr[wid + 1];
  const unsigned* R32 = (const unsigned*)R;
  float a0 = 0.f, a1 = 0.f;
  int i = s;
  for (; i + 7 < e; i += 8) {
    int q0 = csr_src[i],     q1 = csr_src[i + 1], q2 = csr_src[i + 2], q3 = csr_src[i + 3];
    int q4 = csr_src[i + 4], q5 = csr_src[i + 5], q6 = csr_src[i + 6], q7 = csr_src[i + 7];
    unsigned w0 = R32[(size_t)q0 * 64 + lane], w1 = R32[(size_t)q1 * 64 + lane];
    unsigned w2 = R32[(size_t)q2 * 64 + lane], w3 = R32[(size_t)q3 * 64 + lane];
    unsigned w4 = R32[(size_t)q4 * 64 + lane], w5 = R32[(size_t)q5 * 64 + lane];
    unsigned w6 = R32[(size_t)q6 * 64 + lane], w7 = R32[(size_t)q7 * 64 + lane];
    a0 += blo(w0) + blo(w1) + blo(w2) + blo(w3) + blo(w4) + blo(w5) + blo(w6) + blo(w7);
    a1 += bhi(w0) + bhi(w1) + bhi(w2) + bhi(w3) + bhi(w4) + bhi(w5) + bhi(w6) + bhi(w7);
  }
  for (; i < e; ++i) {
    unsigned v = R32[(size_t)csr_src[i] * 64 + lane];
    a0 += blo(v); a1 += bhi(v);
  }
  const int d0 = lane * 2;
  float dg = (float)(e - s);
  float m0 = stats[d0] * (1.f / NN), m1 = stats[d0 + 1] * (1.f / NN);
  float v0 = stats[DD + d0] * (1.f / NN) - m0 * m0;
  float v1 = stats[DD + d0 + 1] * (1.f / NN) - m1 * m1;
  float sc0 = g[d0] * rsqrtf(v0 + BN_EPS), sc1 = g[d0 + 1] * rsqrtf(v1 + BN_EPS);
  float sh0 = b[d0] - m0 * sc0, sh1 = b[d0 + 1] - m1 * sc1;
  float r0 = sc0 * a0 + sh0 * dg;
  float r1 = sc1 * a1 + sh1 * dg;
  unsigned pk = (unsigned)f2b(r0) | ((unsigned)f2b(r1) << 16);
  ((unsigned*)out)[(size_t)wid * 64 + lane] = pk;
}

// ---------------- weight prep ----------------
template<int MODE>
__device__ __forceinline__ void wprep_body(
    const float* __restrict__ W, const float* __restrict__ bias,
    const float* __restrict__ in_stats, const float* __restrict__ in_g,
    const float* __restrict__ in_b,
    const float* __restrict__ res_stats, const float* __restrict__ res_g,
    const float* __restrict__ res_b,
    u16* __restrict__ WT, float* __restrict__ biasP, float* __restrict__ rese) {
  __shared__ float s_s[DD], s_t[DD];
  int t = threadIdx.x;
  if (t < DD) {
    float s = 1.f, tt = 0.f;
    if (MODE == 1) {
      float mean = in_stats[t] * (1.f / NN);
      float var  = in_stats[DD + t] * (1.f / NN) - mean * mean;
      float rs = rsqrtf(var + BN_EPS);
      s = in_g[t] * rs;
      tt = in_b[t] - mean * s;
      float m2 = res_stats[t] * (1.f / NN);
      float v2 = res_stats[DD + t] * (1.f / NN) - m2 * m2;
      float r2 = rsqrtf(v2 + BN_EPS);
      float sc = res_g[t] * r2;
      rese[t] = sc;
      rese[DD + t] = res_b[t] - m2 * sc;
    }
    s_s[t] = s; s_t[t] = tt;
  }
  __syncthreads();
  for (int idx = t; idx < DD * DD; idx += 256) {
    int k = idx >> 7, n = idx & 127;
    WT[n * DD + k] = f2b(W[idx] * s_s[k]);
  }
  if (t < DD) {
    float acc = bias[t];
    if (MODE == 1)
      for (int k = 0; k < DD; ++k) acc += s_t[k] * W[k * DD + t];
    biasP[t] = acc;
  }
}

__global__ void k_wprep0(const float* __restrict__ w_n2l_w, const float* __restrict__ w_n2l_b,
                         const float* __restrict__ conv_w, const float* __restrict__ conv_b,
                         u16* wt0, float* bp0, u16* wt1, float* bp1,
                         u16* wt3, float* bp3, u16* wt5, float* bp5) {
  int blk = blockIdx.x;
  const float* W; const float* bias; u16* WT; float* biasP;
  if (blk == 0)      { W = w_n2l_w;              bias = w_n2l_b;          WT = wt0; biasP = bp0; }
  else if (blk == 1) { W = conv_w;               bias = conv_b;           WT = wt1; biasP = bp1; }
  else if (blk == 2) { W = conv_w + DD * DD;     bias = conv_b + DD;      WT = wt3; biasP = bp3; }
  else               { W = conv_w + 2 * DD * DD; bias = conv_b + 2 * DD;  WT = wt5; biasP = bp5; }
  wprep_body<0>(W, bias, nullptr, nullptr, nullptr, nullptr, nullptr, nullptr,
                WT, biasP, nullptr);
}

__global__ void k_wprep1(const float* __restrict__ W, const float* __restrict__ bias,
                         const float* __restrict__ in_stats, const float* __restrict__ in_g,
                         const float* __restrict__ in_b,
                         const float* __restrict__ res_stats, const float* __restrict__ res_g,
                         const float* __restrict__ res_b,
                         u16* WT, float* biasP, float* rese) {
  wprep_body<1>(W, bias, in_stats, in_g, in_b, res_stats, res_g, res_b, WT, biasP, rese);
}

// swizzled LDS byte address: granule XOR within 8-granule (128B) halves of a 256B row
__device__ __forceinline__ int swz_addr(int row_bytes, int xr, int g, int o) {
  return row_bytes + ((((g & 7) ^ xr) | (g & 8)) << 4) + o;
}

// ---------------- MFMA GEMM, 64-row tiles (3 blocks/CU) ----------------
// MODE 0: A = bf16 buffer (global_load_lds); extra = e2n from agg4
// MODE 1: A = bf16 buffer (global_load_lds); extra = affine(resid)
// MODE 2: A = fp32 buffer, on-the-fly bf16 cvt; extra = e2n from agg4
template<int MODE>
__global__ __launch_bounds__(256, 3)
void k_gemm(const void* __restrict__ Ain, const u16* __restrict__ WT,
            const float* __restrict__ biasP, u16* __restrict__ out,
            float* __restrict__ stats_out,
            const float* __restrict__ rese, const u16* __restrict__ resid,
            const float4* __restrict__ agg4,
            const float* __restrict__ w_e2l, const float* __restrict__ b_e2l) {
  __shared__ __align__(16) u16 lds_a[64 * 128];    // 16 KB, swizzled
  __shared__ __align__(16) u16 lds_b[128 * 128];   // 32 KB, swizzled
  __shared__ float sstats[2 * DD];
  const int tid  = threadIdx.x;
  const int lane = tid & 63;
  const int wv   = tid >> 6;
  const int row0 = blockIdx.x * 64;

  if (tid < 2 * DD) sstats[tid] = 0.f;

  // ---- stage WT (all modes) and A (MODE 0/1) via global_load_lds ----
#pragma unroll
  for (int c = 0; c < 8; ++c) {
    int gidx = (wv * 8 + c) * 64 + lane;
    int row = gidx >> 4, gL = gidx & 15;
    int gS = (gL & 8) | ((gL & 7) ^ (row & 7));
    const u16* gsrcB = WT + (size_t)row * DD + gS * 8;
    u16* ldstB = lds_b + (size_t)(wv * 8 + c) * 512;
    __builtin_amdgcn_global_load_lds(
        (const __attribute__((address_space(1))) unsigned int*)gsrcB,
        (__attribute__((address_space(3))) unsigned int*)ldstB, 16, 0, 0);
  }
  if (MODE != 2) {
#pragma unroll
    for (int c = 0; c < 4; ++c) {
      int gidx = (wv * 4 + c) * 64 + lane;
      int row = gidx >> 4, gL = gidx & 15;
      int gS = (gL & 8) | ((gL & 7) ^ (row & 7));
      int arow = row0 + row; if (arow >= NN) arow = NN - 1;
      const u16* gsrcA = (const u16*)Ain + (size_t)arow * DD + gS * 8;
      u16* ldstA = lds_a + (size_t)(wv * 4 + c) * 512;
      __builtin_amdgcn_global_load_lds(
          (const __attribute__((address_space(1))) unsigned int*)gsrcA,
          (__attribute__((address_space(3))) unsigned int*)ldstA, 16, 0, 0);
    }
  } else {
    const float2* Af = (const float2*)Ain;       // row = 64 float2 (128 f32)
#pragma unroll
    for (int k = 0; k < 16; ++k) {
      int idx = k * 256 + tid;                   // 0..4095
      int r = idx >> 6, ln = idx & 63;
      int n = row0 + r; if (n >= NN) n = NN - 1;
      float2 v = Af[(size_t)n * 64 + ln];
      unsigned pk = (unsigned)f2b(v.x) | ((unsigned)f2b(v.y) << 16);
      int gLn = ln >> 2, oin = (ln & 3) * 4;
      int gS = (gLn & 8) | ((gLn & 7) ^ (r & 7));
      *(unsigned*)((char*)lds_a + r * 256 + gS * 16 + oin) = pk;
    }
  }
  __syncthreads();

  const int colid = lane & 15;
  const int lgrp  = lane >> 4;
  const int o = (lgrp & 1) * 8;

  // A fragments for this wave's 16 rows
  s16x8 afr[4];
  {
    int r = wv * 16 + colid;
    int rb = r << 8, xr = r & 7;
#pragma unroll
    for (int ks = 0; ks < 4; ++ks) {
      int g0 = ks * 4 + (lgrp >> 1);
      uint2 lo = *(const uint2*)((const char*)lds_a + swz_addr(rb, xr, g0, o));
      uint2 hi = *(const uint2*)((const char*)lds_a + swz_addr(rb, xr, g0 + 2, o));
      union { unsigned u[4]; s16x8 v; } pk;
      pk.u[0] = lo.x; pk.u[1] = lo.y; pk.u[2] = hi.x; pk.u[3] = hi.y;
      afr[ks] = pk.v;
    }
  }

  float4 ev[4];
  if (MODE != 1) {
#pragma unroll
    for (int q = 0; q < 4; ++q) {
      int r = row0 + wv * 16 + lgrp * 4 + q;
      if (r >= NN) r = NN - 1;
      ev[q] = agg4[r];
    }
  }

  for (int cf = 0; cf < 8; ++cf) {
    const int col = cf * 16 + colid;
    float bp = biasP[col];
    f32x4 acc;
    if (MODE == 1) {
      float sc = rese[col], sh = rese[DD + col];
#pragma unroll
      for (int q = 0; q < 4; ++q) {
        int r = row0 + wv * 16 + lgrp * 4 + q;
        int rc = r < NN ? r : NN - 1;
        acc[q] = bp + sc * b2f(resid[(size_t)rc * DD + col]) + sh;
      }
    } else {
#pragma unroll
      for (int q = 0; q < 4; ++q) {
        float4 e4 = ev[q];
        acc[q] = bp + e4.x * w_e2l[col] + e4.y * w_e2l[DD + col]
                    + e4.z * w_e2l[2 * DD + col] + e4.w * b_e2l[col];
      }
    }
    {
      int nb = col << 8, xn = col & 7;
#pragma unroll
      for (int ks = 0; ks < 4; ++ks) {
        int g0 = ks * 4 + (lgrp >> 1);
        uint2 lo = *(const uint2*)((const char*)lds_b + swz_addr(nb, xn, g0, o));
        uint2 hi = *(const uint2*)((const char*)lds_b + swz_addr(nb, xn, g0 + 2, o));
        union { unsigned u[4]; s16x8 v; } pk;
        pk.u[0] = lo.x; pk.u[1] = lo.y; pk.u[2] = hi.x; pk.u[3] = hi.y;
        acc = __builtin_amdgcn_mfma_f32_16x16x32_bf16(afr[ks], pk.v, acc, 0, 0, 0);
      }
    }
    float s = 0.f, s2 = 0.f;
#pragma unroll
    for (int q = 0; q < 4; ++q) {
      int r = row0 + wv * 16 + lgrp * 4 + q;
      float v = fmaxf(acc[q], 0.f);
      if (r < NN) {
        out[(size_t)r * DD + col] = f2b(v);
        s += v; s2 += v * v;
      }
    }
    s  += __shfl_xor(s, 16);  s  += __shfl_xor(s, 32);
    s2 += __shfl_xor(s2, 16); s2 += __shfl_xor(s2, 32);
    if (lgrp == 0) {
      atomicAdd(&sstats[col], s);
      atomicAdd(&sstats[DD + col], s2);
    }
  }
  __syncthreads();
  if (tid < 2 * DD) atomicAdd(&stats_out[tid], sstats[tid]);
}

// ---------------- segment max (bf16 input) ----------------
__global__ void k_segmax(const u16* __restrict__ R, const int* __restrict__ g_idx,
                         unsigned* __restrict__ gemb_enc,
                         const float* __restrict__ stats, const float* __restrict__ g,
                         const float* __restrict__ b) {
  int t = blockIdx.x * blockDim.x + threadIdx.x;
  int d = t & (DD - 1);
  int chunk = t >> 7;
  int n0 = chunk * 8;
  if (n0 >= NN) return;
  float mean = stats[d] * (1.f / NN);
  float var  = stats[DD + d] * (1.f / NN) - mean * mean;
  float rs = rsqrtf(var + BN_EPS);
  float scale = g[d] * rs;
  float shift = b[d] - mean * scale;
  int cur = -1; float run = 0.f;
  int nend = n0 + 8; if (nend > NN) nend = NN;
  for (int n = n0; n < nend; ++n) {
    float v = scale * b2f(R[(size_t)n * DD + d]) + shift;
    int gi = g_idx[n];
    if (gi != cur) {
      if (cur >= 0) atomicMax(&gemb_enc[cur * DD + d], enc_f(run));
      cur = gi; run = v;
    } else {
      run = fmaxf(run, v);
    }
  }
  if (cur >= 0) atomicMax(&gemb_enc[cur * DD + d], enc_f(run));
}

// ---------------- readout ----------------
__global__ void k_readout(const unsigned* __restrict__ gemb,
                          const float* __restrict__ W, const float* __restrict__ b,
                          float* __restrict__ out) {
  __shared__ float row[DD];
  int g = blockIdx.x, t = threadIdx.x;
  row[t] = dec_f(gemb[g * DD + t]);
  __syncthreads();
  float acc = b[t];
  for (int d = 0; d < DD; ++d) acc += row[d] * W[d * DD + t];
  out[g * DD + t] = fmaxf(acc, 0.f);
}

extern "C" void kernel_launch(void* const* d_in, const int* in_sizes, int n_in,
                              void* d_out, int out_size, void* d_ws, size_t ws_size,
                              hipStream_t stream) {
  const float* node_feat = (const float*)d_in[0];
  const float* edge_feat = (const float*)d_in[1];
  const int*   efrom     = (const int*)d_in[2];
  const int*   eto       = (const int*)d_in[3];
  const int*   g_idx     = (const int*)d_in[4];
  const float* w_n2l_w   = (const float*)d_in[6];
  const float* w_n2l_b   = (const float*)d_in[7];
  const float* w_e2l_w   = (const float*)d_in[8];   // [4][3][128]
  const float* w_e2l_b   = (const float*)d_in[9];   // [4][128]
  const float* conv_w    = (const float*)d_in[10];  // [3][128][128]
  const float* conv_b    = (const float*)d_in[11];
  const float* l2_w      = (const float*)d_in[12];
  const float* l2_b      = (const float*)d_in[13];
  const float* msg_bn_g  = (const float*)d_in[14];  // [4][128]
  const float* msg_bn_b  = (const float*)d_in[15];
  const float* hid_bn_g  = (const float*)d_in[16];  // [3][128]
  const float* hid_bn_b  = (const float*)d_in[17];
  const float* readout_w = (const float*)d_in[18];
  const float* readout_b = (const float*)d_in[19];
  float* out = (float*)d_out;
  (void)in_sizes; (void)n_in; (void)out_size; (void)ws_size;

  char* ws = (char*)d_ws;
  size_t off = 0;
  auto alloc = [&](size_t bytes) -> void* {
    void* p = ws + off; off += (bytes + 511) & ~(size_t)511; return p;
  };
  u16*      Pb0     = (u16*)alloc((size_t)NN * DD * 2);
  u16*      Pb1     = (u16*)alloc((size_t)NN * DD * 2);
  u16*      Pb2     = (u16*)alloc((size_t)NN * DD * 2);
  float*    agg4    = (float*)alloc((size_t)NN * 4 * 4);
  int*      cursor  = (int*)alloc((size_t)NN * 4);
  int*      row_ptr = (int*)alloc((size_t)(NN + 1) * 4);
  int*      tmp_pos = (int*)alloc((size_t)NE * 4);
  int*      csr_src = (int*)alloc((size_t)NE * 4);
  int*      csr_eid = (int*)alloc((size_t)NE * 4);
  int*      bsum    = (int*)alloc((size_t)NB * 4);
  int*      boff    = (int*)alloc((size_t)NB * 4);
  float*    stats   = (float*)alloc((size_t)7 * 2 * DD * 4);
  unsigned* gemb    = (unsigned*)alloc((size_t)GG * DD * 4);
  u16*      wt[7];
  float*    bp[7];
  float*    re[7];
  for (int i = 0; i < 7; ++i) {
    wt[i] = (u16*)alloc((size_t)DD * DD * 2);
    bp[i] = (float*)alloc((size_t)DD * 4);
    re[i] = (float*)alloc((size_t)2 * DD * 4);
  }

  k_init<<<(NN + 255) / 256, 256, 0, stream>>>(cursor, stats, gemb);
  k_fill1<<<(NE + 255) / 256, 256, 0, stream>>>(eto, cursor, tmp_pos);
  k_scan1<<<NB, SCAN_B, 0, stream>>>(cursor, row_ptr, bsum);
  k_scan2<<<1, 128, 0, stream>>>(bsum, boff, row_ptr);
  k_scan3<<<(NN + 255) / 256, 256, 0, stream>>>(row_ptr, boff);
  k_fill2<<<(NE + 255) / 256, 256, 0, stream>>>(efrom, eto, tmp_pos, row_ptr,
                                                csr_src, csr_eid);
  k_node_ef<<<(NN * 16 + 255) / 256, 256, 0, stream>>>(edge_feat, row_ptr, csr_eid,
                                                       agg4);
  k_wprep0<<<4, 256, 0, stream>>>(w_n2l_w, w_n2l_b, conv_w, conv_b,
                                  wt[0], bp[0], wt[1], bp[1], wt[3], bp[3], wt[5], bp[5]);

  float* stat_msg[4] = { stats + 0*256, stats + 1*256, stats + 2*256, stats + 3*256 };
  float* stat_hid[3] = { stats + 4*256, stats + 5*256, stats + 6*256 };
  const int GEMM_GRID = (NN + 63) / 64;  // 1563

  // GEMM0 (MODE 2): Pb0 = relu(bf16(node_feat) @ w_n2l + b + e2n0); stats -> msg[0]
  k_gemm<2><<<GEMM_GRID, 256, 0, stream>>>(node_feat, wt[0], bp[0], Pb0, stat_msg[0],
      nullptr, nullptr, (const float4*)agg4, w_e2l_w + 0 * 3 * DD, w_e2l_b + 0 * DD);

  u16* R = Pb0; u16* other = Pb1;
  for (int lv = 0; lv < 3; ++lv) {
    int wc = 1 + 2 * lv, wl = 2 + 2 * lv;
    // agg = affine_msg[lv](seg(R[from])) -> other
    k_gather<<<(NN * 64 + 255) / 256, 256, 0, stream>>>(R, other, row_ptr, csr_src,
        stat_msg[lv], msg_bn_g + lv * DD, msg_bn_b + lv * DD);
    // conv (MODE 0): Pb2 = relu(other @ conv_w[lv] + conv_b + e2n[lv+1]); stats -> hid[lv]
    k_gemm<0><<<GEMM_GRID, 256, 0, stream>>>(other, wt[wc], bp[wc], Pb2, stat_hid[lv],
        nullptr, nullptr, (const float4*)agg4,
        w_e2l_w + (size_t)(lv + 1) * 3 * DD, w_e2l_b + (lv + 1) * DD);
    // l2 (MODE 1): other = relu(norm_hid(Pb2) @ l2_w[lv] + l2_b + affine_msg[lv](R))
    k_wprep1<<<1, 256, 0, stream>>>(l2_w + (size_t)lv * DD * DD, l2_b + lv * DD,
        stat_hid[lv], hid_bn_g + lv * DD, hid_bn_b + lv * DD,
        stat_msg[lv], msg_bn_g + lv * DD, msg_bn_b + lv * DD, wt[wl], bp[wl], re[wl]);
    k_gemm<1><<<GEMM_GRID, 256, 0, stream>>>(Pb2, wt[wl], bp[wl], other, stat_msg[lv + 1],
        re[wl], R, nullptr, nullptr, nullptr);
    u16* t = R; R = other; other = t;
  }

  k_segmax<<<(NN / 8) * DD / 256, 256, 0, stream>>>(
      R, g_idx, gemb, stat_msg[3], msg_bn_g + 3 * DD, msg_bn_b + 3 * DD);
  k_readout<<<GG, DD, 0, stream>>>(gemb, readout_w, readout_b, out);
}

// Round 6
// 802.830 us; speedup vs baseline: 1.3307x; 1.0268x over previous
//
#include <hip/hip_runtime.h>
#include <hip/hip_bf16.h>

#define NN 100000
#define NE 1600000
#define DD 128
#define GG 64
#define BN_EPS 1e-5f
#define NCOPY 16

typedef unsigned short u16;
using f32x4 = __attribute__((ext_vector_type(4))) float;
using s16x8 = __attribute__((ext_vector_type(8))) short;

constexpr int SCAN_B = 1024;
constexpr int NB = (NN + SCAN_B - 1) / SCAN_B;  // 98

__device__ __forceinline__ unsigned enc_f(float v) {
  unsigned u = __float_as_uint(v);
  return (u & 0x80000000u) ? ~u : (u | 0x80000000u);
}
__device__ __forceinline__ float dec_f(unsigned k) {
  unsigned u = (k & 0x80000000u) ? (k & 0x7FFFFFFFu) : ~k;
  return __uint_as_float(u);
}
__device__ __forceinline__ u16 f2b(float x) {
  __hip_bfloat16 h = __float2bfloat16(x);
  return *(u16*)&h;
}
__device__ __forceinline__ float b2f(u16 u) {
  unsigned v = ((unsigned)u) << 16;
  return __uint_as_float(v);
}
__device__ __forceinline__ float blo(unsigned v) { return __uint_as_float(v << 16); }
__device__ __forceinline__ float bhi(unsigned v) { return __uint_as_float(v & 0xFFFF0000u); }

// ---------------- init ----------------
__global__ void k_init(int* cursor, float* stats_raw, float* stats_fin,
                       unsigned* gemb_enc) {
  int i = blockIdx.x * blockDim.x + threadIdx.x;
  if (i < NN) cursor[i] = 0;
  if (i < 7 * NCOPY * 256) stats_raw[i] = 0.f;
  if (i < 4 * 256) stats_fin[i] = 0.f;
  if (i < GG*DD) gemb_enc[i] = 0x007FFFFFu;  // enc(-inf)
}

// ---------------- CSR build, pass 1 ----------------
__global__ void k_fill1(const int* __restrict__ to, int* cursor, int* __restrict__ tmp_pos) {
  int e = blockIdx.x * blockDim.x + threadIdx.x;
  if (e >= NE) return;
  tmp_pos[e] = atomicAdd(&cursor[to[e]], 1);
}

// ---------------- scan over cursor(=deg) -> exclusive row_ptr ----------------
__global__ void k_scan1(const int* __restrict__ deg, int* row_ptr, int* bsum) {
  __shared__ int lds[SCAN_B];
  int t = threadIdx.x, i = blockIdx.x * SCAN_B + t;
  int v = (i < NN) ? deg[i] : 0;
  lds[t] = v;
  __syncthreads();
  for (int off = 1; off < SCAN_B; off <<= 1) {
    int add = (t >= off) ? lds[t - off] : 0;
    __syncthreads();
    lds[t] += add;
    __syncthreads();
  }
  if (i < NN) row_ptr[i] = lds[t] - v;
  if (t == SCAN_B - 1) bsum[blockIdx.x] = lds[t];
}

__global__ void k_scan2(const int* __restrict__ bsum, int* boff, int* row_ptr) {
  __shared__ int lds[128];
  int t = threadIdx.x;
  int v = (t < NB) ? bsum[t] : 0;
  lds[t] = v;
  __syncthreads();
  for (int off = 1; off < 128; off <<= 1) {
    int add = (t >= off) ? lds[t - off] : 0;
    __syncthreads();
    lds[t] += add;
    __syncthreads();
  }
  if (t < NB) boff[t] = lds[t] - v;
  if (t == 127) row_ptr[NN] = lds[127];
}

__global__ void k_scan3(int* row_ptr, const int* __restrict__ boff) {
  int i = blockIdx.x * blockDim.x + threadIdx.x;
  if (i >= NN) return;
  row_ptr[i] += boff[i >> 10];
}

// ---------------- CSR build, pass 2: scatter (no atomics) ----------------
__global__ void k_fill2(const int* __restrict__ from, const int* __restrict__ to,
                        const int* __restrict__ tmp_pos, const int* __restrict__ row_ptr,
                        int* __restrict__ csr_src, int* __restrict__ csr_eid) {
  int e = blockIdx.x * blockDim.x + threadIdx.x;
  if (e >= NE) return;
  int pos = row_ptr[to[e]] + tmp_pos[e];
  csr_src[pos] = from[e];
  csr_eid[pos] = e;
}

// ---------------- per-node raw edge-feature aggregation: 16 lanes/node ----------------
__global__ void k_node_ef(const float* __restrict__ ef, const int* __restrict__ row_ptr,
                          const int* __restrict__ csr_eid, float* __restrict__ agg4) {
  int grp = (blockIdx.x * 256 + threadIdx.x) >> 4;   // node
  if (grp >= NN) return;
  int l = threadIdx.x & 15;
  int s = row_ptr[grp], e = row_ptr[grp + 1];
  float a0 = 0.f, a1 = 0.f, a2 = 0.f;
  for (int i = s + l; i < e; i += 16) {
    int eid = csr_eid[i];
    a0 += ef[(size_t)eid * 3 + 0];
    a1 += ef[(size_t)eid * 3 + 1];
    a2 += ef[(size_t)eid * 3 + 2];
  }
#pragma unroll
  for (int off = 8; off; off >>= 1) {
    a0 += __shfl_down(a0, off, 16);
    a1 += __shfl_down(a1, off, 16);
    a2 += __shfl_down(a2, off, 16);
  }
  if (l == 0)
    ((float4*)agg4)[grp] = make_float4(a0, a1, a2, (float)(e - s));
}

// ---------------- reduce 16 stat copies -> finalized 256 floats ----------------
__global__ void k_redstat(const float* __restrict__ raw, float* __restrict__ fin) {
  int c = threadIdx.x;  // 256
  float s = 0.f;
#pragma unroll
  for (int i = 0; i < NCOPY; ++i) s += raw[i * 256 + c];
  fin[c] = s;
}

// ---------------- neighbor gather: wave per node, 2 dims/lane, 8-deep unroll ----------------
__global__ __launch_bounds__(256)
void k_gather(const u16* __restrict__ R, u16* __restrict__ out,
              const int* __restrict__ row_ptr, const int* __restrict__ csr_src,
              const float* __restrict__ stats, const float* __restrict__ g,
              const float* __restrict__ b) {
  const int wid = (blockIdx.x * 256 + threadIdx.x) >> 6;   // node
  if (wid >= NN) return;
  const int lane = threadIdx.x & 63;
  const int s = row_ptr[wid], e = row_ptr[wid + 1];
  const unsigned* R32 = (const unsigned*)R;
  float a0 = 0.f, a1 = 0.f;
  int i = s;
  for (; i + 7 < e; i += 8) {
    int q0 = csr_src[i],     q1 = csr_src[i + 1], q2 = csr_src[i + 2], q3 = csr_src[i + 3];
    int q4 = csr_src[i + 4], q5 = csr_src[i + 5], q6 = csr_src[i + 6], q7 = csr_src[i + 7];
    unsigned w0 = R32[(size_t)q0 * 64 + lane], w1 = R32[(size_t)q1 * 64 + lane];
    unsigned w2 = R32[(size_t)q2 * 64 + lane], w3 = R32[(size_t)q3 * 64 + lane];
    unsigned w4 = R32[(size_t)q4 * 64 + lane], w5 = R32[(size_t)q5 * 64 + lane];
    unsigned w6 = R32[(size_t)q6 * 64 + lane], w7 = R32[(size_t)q7 * 64 + lane];
    a0 += blo(w0) + blo(w1) + blo(w2) + blo(w3) + blo(w4) + blo(w5) + blo(w6) + blo(w7);
    a1 += bhi(w0) + bhi(w1) + bhi(w2) + bhi(w3) + bhi(w4) + bhi(w5) + bhi(w6) + bhi(w7);
  }
  for (; i < e; ++i) {
    unsigned v = R32[(size_t)csr_src[i] * 64 + lane];
    a0 += blo(v); a1 += bhi(v);
  }
  const int d0 = lane * 2;
  float dg = (float)(e - s);
  float m0 = stats[d0] * (1.f / NN), m1 = stats[d0 + 1] * (1.f / NN);
  float v0 = stats[DD + d0] * (1.f / NN) - m0 * m0;
  float v1 = stats[DD + d0 + 1] * (1.f / NN) - m1 * m1;
  float sc0 = g[d0] * rsqrtf(v0 + BN_EPS), sc1 = g[d0 + 1] * rsqrtf(v1 + BN_EPS);
  float sh0 = b[d0] - m0 * sc0, sh1 = b[d0 + 1] - m1 * sc1;
  float r0 = sc0 * a0 + sh0 * dg;
  float r1 = sc1 * a1 + sh1 * dg;
  unsigned pk = (unsigned)f2b(r0) | ((unsigned)f2b(r1) << 16);
  ((unsigned*)out)[(size_t)wid * 64 + lane] = pk;
}

// ---------------- weight prep ----------------
// MODE 1: in_stats/res_stats are RAW (NCOPY copies) — summed here.
template<int MODE>
__device__ __forceinline__ void wprep_body(
    const float* __restrict__ W, const float* __restrict__ bias,
    const float* __restrict__ in_stats, const float* __restrict__ in_g,
    const float* __restrict__ in_b,
    const float* __restrict__ res_stats, const float* __restrict__ res_g,
    const float* __restrict__ res_b,
    u16* __restrict__ WT, float* __restrict__ biasP, float* __restrict__ rese) {
  __shared__ float s_s[DD], s_t[DD];
  int t = threadIdx.x;
  if (t < DD) {
    float s = 1.f, tt = 0.f;
    if (MODE == 1) {
      float s1 = 0.f, s2 = 0.f, r1 = 0.f, r2 = 0.f;
#pragma unroll
      for (int i = 0; i < NCOPY; ++i) {
        s1 += in_stats[i * 256 + t];
        s2 += in_stats[i * 256 + DD + t];
        r1 += res_stats[i * 256 + t];
        r2 += res_stats[i * 256 + DD + t];
      }
      float mean = s1 * (1.f / NN);
      float var  = s2 * (1.f / NN) - mean * mean;
      float rs = rsqrtf(var + BN_EPS);
      s = in_g[t] * rs;
      tt = in_b[t] - mean * s;
      float m2 = r1 * (1.f / NN);
      float v2 = r2 * (1.f / NN) - m2 * m2;
      float rr = rsqrtf(v2 + BN_EPS);
      float sc = res_g[t] * rr;
      rese[t] = sc;
      rese[DD + t] = res_b[t] - m2 * sc;
    }
    s_s[t] = s; s_t[t] = tt;
  }
  __syncthreads();
  for (int idx = t; idx < DD * DD; idx += 256) {
    int k = idx >> 7, n = idx & 127;
    WT[n * DD + k] = f2b(W[idx] * s_s[k]);
  }
  if (t < DD) {
    float acc = bias[t];
    if (MODE == 1)
      for (int k = 0; k < DD; ++k) acc += s_t[k] * W[k * DD + t];
    biasP[t] = acc;
  }
}

__global__ void k_wprep0(const float* __restrict__ w_n2l_w, const float* __restrict__ w_n2l_b,
                         const float* __restrict__ conv_w, const float* __restrict__ conv_b,
                         u16* wt0, float* bp0, u16* wt1, float* bp1,
                         u16* wt3, float* bp3, u16* wt5, float* bp5) {
  int blk = blockIdx.x;
  const float* W; const float* bias; u16* WT; float* biasP;
  if (blk == 0)      { W = w_n2l_w;              bias = w_n2l_b;          WT = wt0; biasP = bp0; }
  else if (blk == 1) { W = conv_w;               bias = conv_b;           WT = wt1; biasP = bp1; }
  else if (blk == 2) { W = conv_w + DD * DD;     bias = conv_b + DD;      WT = wt3; biasP = bp3; }
  else               { W = conv_w + 2 * DD * DD; bias = conv_b + 2 * DD;  WT = wt5; biasP = bp5; }
  wprep_body<0>(W, bias, nullptr, nullptr, nullptr, nullptr, nullptr, nullptr,
                WT, biasP, nullptr);
}

__global__ void k_wprep1(const float* __restrict__ W, const float* __restrict__ bias,
                         const float* __restrict__ in_stats, const float* __restrict__ in_g,
                         const float* __restrict__ in_b,
                         const float* __restrict__ res_stats, const float* __restrict__ res_g,
                         const float* __restrict__ res_b,
                         u16* WT, float* biasP, float* rese) {
  wprep_body<1>(W, bias, in_stats, in_g, in_b, res_stats, res_g, res_b, WT, biasP, rese);
}

// swizzled LDS byte address: granule XOR within 8-granule (128B) halves of a 256B row
__device__ __forceinline__ int swz_addr(int row_bytes, int xr, int g, int o) {
  return row_bytes + ((((g & 7) ^ xr) | (g & 8)) << 4) + o;
}

// ---------------- MFMA GEMM, 128-row tiles, B in registers (no LDS for B) ----------------
// MODE 0: A bf16 (global_load_lds); extra = e2n from agg4
// MODE 1: A bf16 (global_load_lds); extra = affine(resid)
// MODE 2: A fp32, on-the-fly bf16 cvt; extra = e2n from agg4
template<int MODE>
__global__ __launch_bounds__(256, 4)
void k_gemm(const void* __restrict__ Ain, const u16* __restrict__ WT,
            const float* __restrict__ biasP, u16* __restrict__ out,
            float* __restrict__ stats_out,
            const float* __restrict__ rese, const u16* __restrict__ resid,
            const float4* __restrict__ agg4,
            const float* __restrict__ w_e2l, const float* __restrict__ b_e2l) {
  __shared__ __align__(16) u16 lds_a[128 * 128];   // 32 KB, swizzled
  __shared__ float sstats[256];
  const int tid  = threadIdx.x;
  const int lane = tid & 63;
  const int wv   = tid >> 6;
  const int row0 = blockIdx.x * 128;

  sstats[tid] = 0.f;

  // ---- stage A ----
  if (MODE != 2) {
#pragma unroll
    for (int c = 0; c < 8; ++c) {
      int gidx = (wv * 8 + c) * 64 + lane;
      int row = gidx >> 4, gL = gidx & 15;
      int gS = (gL & 8) | ((gL & 7) ^ (row & 7));
      int arow = row0 + row; if (arow >= NN) arow = NN - 1;
      const u16* gsrcA = (const u16*)Ain + (size_t)arow * DD + gS * 8;
      u16* ldstA = lds_a + (size_t)(wv * 8 + c) * 512;
      __builtin_amdgcn_global_load_lds(
          (const __attribute__((address_space(1))) unsigned int*)gsrcA,
          (__attribute__((address_space(3))) unsigned int*)ldstA, 16, 0, 0);
    }
  } else {
    const float2* Af = (const float2*)Ain;       // row = 64 float2 (128 f32)
#pragma unroll
    for (int k = 0; k < 32; ++k) {
      int idx = k * 256 + tid;                   // 0..8191
      int r = idx >> 6, ln = idx & 63;
      int n = row0 + r; if (n >= NN) n = NN - 1;
      float2 v = Af[(size_t)n * 64 + ln];
      unsigned pk = (unsigned)f2b(v.x) | ((unsigned)f2b(v.y) << 16);
      int gLn = ln >> 2, oin = (ln & 3) * 4;
      int gS = (gLn & 8) | ((gLn & 7) ^ (r & 7));
      *(unsigned*)((char*)lds_a + r * 256 + gS * 16 + oin) = pk;
    }
  }
  __syncthreads();

  const int colid = lane & 15;
  const int lgrp  = lane >> 4;
  const int rowbase = wv * 32;
  const int o = (lgrp & 1) * 8;
  const int oo = (lgrp & 1);

  // A fragments for this wave's 32 rows
  s16x8 afr[2][4];
#pragma unroll
  for (int rf = 0; rf < 2; ++rf) {
    int r = rowbase + rf * 16 + colid;
    int rb = r << 8, xr = r & 7;
#pragma unroll
    for (int ks = 0; ks < 4; ++ks) {
      int g0 = ks * 4 + (lgrp >> 1);
      uint2 lo = *(const uint2*)((const char*)lds_a + swz_addr(rb, xr, g0, o));
      uint2 hi = *(const uint2*)((const char*)lds_a + swz_addr(rb, xr, g0 + 2, o));
      union { unsigned u[4]; s16x8 v; } pk;
      pk.u[0] = lo.x; pk.u[1] = lo.y; pk.u[2] = hi.x; pk.u[3] = hi.y;
      afr[rf][ks] = pk.v;
    }
  }

  const uint2* wt2 = (const uint2*)WT;           // row = 32 uint2 (128 bf16)

#pragma unroll 1
  for (int cf = 0; cf < 8; ++cf) {
    const int col = cf * 16 + colid;
    const float bp = biasP[col];
    f32x4 acc0 = {bp, bp, bp, bp}, acc1 = {bp, bp, bp, bp};
    // B fragments straight from global (L2-resident WT)
#pragma unroll
    for (int ks = 0; ks < 4; ++ks) {
      int g0 = ks * 4 + (lgrp >> 1);
      uint2 lo = wt2[(size_t)col * 32 + g0 * 2 + oo];
      uint2 hi = wt2[(size_t)col * 32 + (g0 + 2) * 2 + oo];
      union { unsigned u[4]; s16x8 v; } pk;
      pk.u[0] = lo.x; pk.u[1] = lo.y; pk.u[2] = hi.x; pk.u[3] = hi.y;
      acc0 = __builtin_amdgcn_mfma_f32_16x16x32_bf16(afr[0][ks], pk.v, acc0, 0, 0, 0);
      acc1 = __builtin_amdgcn_mfma_f32_16x16x32_bf16(afr[1][ks], pk.v, acc1, 0, 0, 0);
    }
    // epilogue: add extra, relu, bf16 store, column stats
    float s = 0.f, s2 = 0.f;
    float sc, sh, we0, we1, we2, be;
    if (MODE == 1) { sc = rese[col]; sh = rese[DD + col]; }
    else { we0 = w_e2l[col]; we1 = w_e2l[DD + col]; we2 = w_e2l[2 * DD + col];
           be = b_e2l[col]; }
#pragma unroll
    for (int rf = 0; rf < 2; ++rf)
#pragma unroll
      for (int q = 0; q < 4; ++q) {
        int r = row0 + rowbase + rf * 16 + lgrp * 4 + q;
        int rc = r < NN ? r : NN - 1;
        float v = (rf == 0 ? acc0[q] : acc1[q]);
        if (MODE == 1) {
          v += sc * b2f(resid[(size_t)rc * DD + col]) + sh;
        } else {
          float4 e4 = agg4[rc];
          v += e4.x * we0 + e4.y * we1 + e4.z * we2 + e4.w * be;
        }
        v = fmaxf(v, 0.f);
        if (r < NN) {
          out[(size_t)r * DD + col] = f2b(v);
          s += v; s2 += v * v;
        }
      }
    s  += __shfl_xor(s, 16);  s  += __shfl_xor(s, 32);
    s2 += __shfl_xor(s2, 16); s2 += __shfl_xor(s2, 32);
    if (lgrp == 0) {
      atomicAdd(&sstats[col], s);
      atomicAdd(&sstats[DD + col], s2);
    }
  }
  __syncthreads();
  atomicAdd(&stats_out[(blockIdx.x & (NCOPY - 1)) * 256 + tid], sstats[tid]);
}

// ---------------- segment max (bf16 input) ----------------
__global__ void k_segmax(const u16* __restrict__ R, const int* __restrict__ g_idx,
                         unsigned* __restrict__ gemb_enc,
                         const float* __restrict__ stats, const float* __restrict__ g,
                         const float* __restrict__ b) {
  int t = blockIdx.x * blockDim.x + threadIdx.x;
  int d = t & (DD - 1);
  int chunk = t >> 7;
  int n0 = chunk * 8;
  if (n0 >= NN) return;
  float mean = stats[d] * (1.f / NN);
  float var  = stats[DD + d] * (1.f / NN) - mean * mean;
  float rs = rsqrtf(var + BN_EPS);
  float scale = g[d] * rs;
  float shift = b[d] - mean * scale;
  int cur = -1; float run = 0.f;
  int nend = n0 + 8; if (nend > NN) nend = NN;
  for (int n = n0; n < nend; ++n) {
    float v = scale * b2f(R[(size_t)n * DD + d]) + shift;
    int gi = g_idx[n];
    if (gi != cur) {
      if (cur >= 0) atomicMax(&gemb_enc[cur * DD + d], enc_f(run));
      cur = gi; run = v;
    } else {
      run = fmaxf(run, v);
    }
  }
  if (cur >= 0) atomicMax(&gemb_enc[cur * DD + d], enc_f(run));
}

// ---------------- readout ----------------
__global__ void k_readout(const unsigned* __restrict__ gemb,
                          const float* __restrict__ W, const float* __restrict__ b,
                          float* __restrict__ out) {
  __shared__ float row[DD];
  int g = blockIdx.x, t = threadIdx.x;
  row[t] = dec_f(gemb[g * DD + t]);
  __syncthreads();
  float acc = b[t];
  for (int d = 0; d < DD; ++d) acc += row[d] * W[d * DD + t];
  out[g * DD + t] = fmaxf(acc, 0.f);
}

extern "C" void kernel_launch(void* const* d_in, const int* in_sizes, int n_in,
                              void* d_out, int out_size, void* d_ws, size_t ws_size,
                              hipStream_t stream) {
  const float* node_feat = (const float*)d_in[0];
  const float* edge_feat = (const float*)d_in[1];
  const int*   efrom     = (const int*)d_in[2];
  const int*   eto       = (const int*)d_in[3];
  const int*   g_idx     = (const int*)d_in[4];
  const float* w_n2l_w   = (const float*)d_in[6];
  const float* w_n2l_b   = (const float*)d_in[7];
  const float* w_e2l_w   = (const float*)d_in[8];   // [4][3][128]
  const float* w_e2l_b   = (const float*)d_in[9];   // [4][128]
  const float* conv_w    = (const float*)d_in[10];  // [3][128][128]
  const float* conv_b    = (const float*)d_in[11];
  const float* l2_w      = (const float*)d_in[12];
  const float* l2_b      = (const float*)d_in[13];
  const float* msg_bn_g  = (const float*)d_in[14];  // [4][128]
  const float* msg_bn_b  = (const float*)d_in[15];
  const float* hid_bn_g  = (const float*)d_in[16];  // [3][128]
  const float* hid_bn_b  = (const float*)d_in[17];
  const float* readout_w = (const float*)d_in[18];
  const float* readout_b = (const float*)d_in[19];
  float* out = (float*)d_out;
  (void)in_sizes; (void)n_in; (void)out_size; (void)ws_size;

  char* ws = (char*)d_ws;
  size_t off = 0;
  auto alloc = [&](size_t bytes) -> void* {
    void* p = ws + off; off += (bytes + 511) & ~(size_t)511; return p;
  };
  u16*      Pb0     = (u16*)alloc((size_t)NN * DD * 2);
  u16*      Pb1     = (u16*)alloc((size_t)NN * DD * 2);
  u16*      Pb2     = (u16*)alloc((size_t)NN * DD * 2);
  float*    agg4    = (float*)alloc((size_t)NN * 4 * 4);
  int*      cursor  = (int*)alloc((size_t)NN * 4);
  int*      row_ptr = (int*)alloc((size_t)(NN + 1) * 4);
  int*      tmp_pos = (int*)alloc((size_t)NE * 4);
  int*      csr_src = (int*)alloc((size_t)NE * 4);
  int*      csr_eid = (int*)alloc((size_t)NE * 4);
  int*      bsum    = (int*)alloc((size_t)NB * 4);
  int*      boff    = (int*)alloc((size_t)NB * 4);
  float*    stats   = (float*)alloc((size_t)7 * NCOPY * 256 * 4);  // raw copies
  float*    statfin = (float*)alloc((size_t)4 * 256 * 4);          // finalized msg stats
  unsigned* gemb    = (unsigned*)alloc((size_t)GG * DD * 4);
  u16*      wt[7];
  float*    bp[7];
  float*    re[7];
  for (int i = 0; i < 7; ++i) {
    wt[i] = (u16*)alloc((size_t)DD * DD * 2);
    bp[i] = (float*)alloc((size_t)DD * 4);
    re[i] = (float*)alloc((size_t)2 * DD * 4);
  }

  k_init<<<(NN + 255) / 256, 256, 0, stream>>>(cursor, stats, statfin, gemb);
  k_fill1<<<(NE + 255) / 256, 256, 0, stream>>>(eto, cursor, tmp_pos);
  k_scan1<<<NB, SCAN_B, 0, stream>>>(cursor, row_ptr, bsum);
  k_scan2<<<1, 128, 0, stream>>>(bsum, boff, row_ptr);
  k_scan3<<<(NN + 255) / 256, 256, 0, stream>>>(row_ptr, boff);
  k_fill2<<<(NE + 255) / 256, 256, 0, stream>>>(efrom, eto, tmp_pos, row_ptr,
                                                csr_src, csr_eid);
  k_node_ef<<<(NN * 16 + 255) / 256, 256, 0, stream>>>(edge_feat, row_ptr, csr_eid,
                                                       agg4);
  k_wprep0<<<4, 256, 0, stream>>>(w_n2l_w, w_n2l_b, conv_w, conv_b,
                                  wt[0], bp[0], wt[1], bp[1], wt[3], bp[3], wt[5], bp[5]);

  // raw stat buffers: [msg0..msg3, hid0..hid2] x (NCOPY*256)
  float* msg_raw[4] = { stats + 0*NCOPY*256, stats + 1*NCOPY*256,
                        stats + 2*NCOPY*256, stats + 3*NCOPY*256 };
  float* hid_raw[3] = { stats + 4*NCOPY*256, stats + 5*NCOPY*256, stats + 6*NCOPY*256 };
  float* msg_fin[4] = { statfin, statfin + 256, statfin + 512, statfin + 768 };
  const int GEMM_GRID = (NN + 127) / 128;  // 782

  // GEMM0 (MODE 2): Pb0 = relu(bf16(node_feat) @ w_n2l + b + e2n0); raw stats -> msg0
  k_gemm<2><<<GEMM_GRID, 256, 0, stream>>>(node_feat, wt[0], bp[0], Pb0, msg_raw[0],
      nullptr, nullptr, (const float4*)agg4, w_e2l_w + 0 * 3 * DD, w_e2l_b + 0 * DD);
  k_redstat<<<1, 256, 0, stream>>>(msg_raw[0], msg_fin[0]);

  u16* R = Pb0; u16* other = Pb1;
  for (int lv = 0; lv < 3; ++lv) {
    int wc = 1 + 2 * lv, wl = 2 + 2 * lv;
    // agg = affine_msg[lv](seg(R[from])) -> other
    k_gather<<<(NN * 64 + 255) / 256, 256, 0, stream>>>(R, other, row_ptr, csr_src,
        msg_fin[lv], msg_bn_g + lv * DD, msg_bn_b + lv * DD);
    // conv (MODE 0): Pb2 = relu(other @ conv_w[lv] + conv_b + e2n[lv+1]); raw -> hid[lv]
    k_gemm<0><<<GEMM_GRID, 256, 0, stream>>>(other, wt[wc], bp[wc], Pb2, hid_raw[lv],
        nullptr, nullptr, (const float4*)agg4,
        w_e2l_w + (size_t)(lv + 1) * 3 * DD, w_e2l_b + (lv + 1) * DD);
    // l2 (MODE 1): other = relu(norm_hid(Pb2) @ l2_w[lv] + l2_b + affine_msg[lv](R))
    k_wprep1<<<1, 256, 0, stream>>>(l2_w + (size_t)lv * DD * DD, l2_b + lv * DD,
        hid_raw[lv], hid_bn_g + lv * DD, hid_bn_b + lv * DD,
        msg_raw[lv], msg_bn_g + lv * DD, msg_bn_b + lv * DD, wt[wl], bp[wl], re[wl]);
    k_gemm<1><<<GEMM_GRID, 256, 0, stream>>>(Pb2, wt[wl], bp[wl], other, msg_raw[lv + 1],
        re[wl], R, nullptr, nullptr, nullptr);
    k_redstat<<<1, 256, 0, stream>>>(msg_raw[lv + 1], msg_fin[lv + 1]);
    u16* t = R; R = other; other = t;
  }

  k_segmax<<<(NN / 8) * DD / 256, 256, 0, stream>>>(
      R, g_idx, gemb, msg_fin[3], msg_bn_g + 3 * DD, msg_bn_b + 3 * DD);
  k_readout<<<GG, DD, 0, stream>>>(gemb, readout_w, readout_b, out);
}

// Round 7
// 650.058 us; speedup vs baseline: 1.6434x; 1.2350x over previous
//
#include <hip/hip_runtime.h>
#include <hip/hip_bf16.h>

#define NN 100000
#define NE 1600000
#define DD 128
#define GG 64
#define BN_EPS 1e-5f
#define NCOPY 16

typedef unsigned short u16;
using f32x4 = __attribute__((ext_vector_type(4))) float;
using s16x8 = __attribute__((ext_vector_type(8))) short;

constexpr int SCAN_B = 1024;
constexpr int NB = (NN + SCAN_B - 1) / SCAN_B;  // 98

__device__ __forceinline__ unsigned enc_f(float v) {
  unsigned u = __float_as_uint(v);
  return (u & 0x80000000u) ? ~u : (u | 0x80000000u);
}
__device__ __forceinline__ float dec_f(unsigned k) {
  unsigned u = (k & 0x80000000u) ? (k & 0x7FFFFFFFu) : ~k;
  return __uint_as_float(u);
}
__device__ __forceinline__ u16 f2b(float x) {
  __hip_bfloat16 h = __float2bfloat16(x);
  return *(u16*)&h;
}
__device__ __forceinline__ float b2f(u16 u) {
  unsigned v = ((unsigned)u) << 16;
  return __uint_as_float(v);
}
__device__ __forceinline__ float blo(unsigned v) { return __uint_as_float(v << 16); }
__device__ __forceinline__ float bhi(unsigned v) { return __uint_as_float(v & 0xFFFF0000u); }

// ---------------- init ----------------
__global__ void k_init(int* cursor, float* stats_raw, float* stats_fin,
                       unsigned* gemb_enc) {
  int i = blockIdx.x * blockDim.x + threadIdx.x;
  if (i < NN) cursor[i] = 0;
  if (i < 7 * NCOPY * 256) stats_raw[i] = 0.f;
  if (i < 4 * 256) stats_fin[i] = 0.f;
  if (i < GG*DD) gemb_enc[i] = 0x007FFFFFu;  // enc(-inf)
}

// ---------------- CSR build, pass 1 ----------------
__global__ void k_fill1(const int* __restrict__ to, int* cursor, int* __restrict__ tmp_pos) {
  int e = blockIdx.x * blockDim.x + threadIdx.x;
  if (e >= NE) return;
  tmp_pos[e] = atomicAdd(&cursor[to[e]], 1);
}

// ---------------- scan over cursor(=deg) -> exclusive row_ptr ----------------
__global__ void k_scan1(const int* __restrict__ deg, int* row_ptr, int* bsum) {
  __shared__ int lds[SCAN_B];
  int t = threadIdx.x, i = blockIdx.x * SCAN_B + t;
  int v = (i < NN) ? deg[i] : 0;
  lds[t] = v;
  __syncthreads();
  for (int off = 1; off < SCAN_B; off <<= 1) {
    int add = (t >= off) ? lds[t - off] : 0;
    __syncthreads();
    lds[t] += add;
    __syncthreads();
  }
  if (i < NN) row_ptr[i] = lds[t] - v;
  if (t == SCAN_B - 1) bsum[blockIdx.x] = lds[t];
}

__global__ void k_scan2(const int* __restrict__ bsum, int* boff, int* row_ptr) {
  __shared__ int lds[128];
  int t = threadIdx.x;
  int v = (t < NB) ? bsum[t] : 0;
  lds[t] = v;
  __syncthreads();
  for (int off = 1; off < 128; off <<= 1) {
    int add = (t >= off) ? lds[t - off] : 0;
    __syncthreads();
    lds[t] += add;
    __syncthreads();
  }
  if (t < NB) boff[t] = lds[t] - v;
  if (t == 127) row_ptr[NN] = lds[127];
}

__global__ void k_scan3(int* row_ptr, const int* __restrict__ boff) {
  int i = blockIdx.x * blockDim.x + threadIdx.x;
  if (i >= NN) return;
  row_ptr[i] += boff[i >> 10];
}

// ---------------- CSR build, pass 2: scatter (no atomics) ----------------
__global__ void k_fill2(const int* __restrict__ from, const int* __restrict__ to,
                        const int* __restrict__ tmp_pos, const int* __restrict__ row_ptr,
                        int* __restrict__ csr_src, int* __restrict__ csr_eid) {
  int e = blockIdx.x * blockDim.x + threadIdx.x;
  if (e >= NE) return;
  int pos = row_ptr[to[e]] + tmp_pos[e];
  csr_src[pos] = from[e];
  csr_eid[pos] = e;
}

// ---------------- per-node raw edge-feature aggregation: 16 lanes/node ----------------
__global__ void k_node_ef(const float* __restrict__ ef, const int* __restrict__ row_ptr,
                          const int* __restrict__ csr_eid, float* __restrict__ agg4) {
  int grp = (blockIdx.x * 256 + threadIdx.x) >> 4;   // node
  if (grp >= NN) return;
  int l = threadIdx.x & 15;
  int s = row_ptr[grp], e = row_ptr[grp + 1];
  float a0 = 0.f, a1 = 0.f, a2 = 0.f;
  for (int i = s + l; i < e; i += 16) {
    int eid = csr_eid[i];
    a0 += ef[(size_t)eid * 3 + 0];
    a1 += ef[(size_t)eid * 3 + 1];
    a2 += ef[(size_t)eid * 3 + 2];
  }
#pragma unroll
  for (int off = 8; off; off >>= 1) {
    a0 += __shfl_down(a0, off, 16);
    a1 += __shfl_down(a1, off, 16);
    a2 += __shfl_down(a2, off, 16);
  }
  if (l == 0)
    ((float4*)agg4)[grp] = make_float4(a0, a1, a2, (float)(e - s));
}

// ---------------- reduce 16 stat copies -> finalized 256 floats ----------------
__global__ void k_redstat(const float* __restrict__ raw, float* __restrict__ fin) {
  int c = threadIdx.x;  // 256
  float s = 0.f;
#pragma unroll
  for (int i = 0; i < NCOPY; ++i) s += raw[i * 256 + c];
  fin[c] = s;
}

// ---------------- neighbor gather: wave per node, 2 dims/lane, 8-deep unroll ----------------
__global__ __launch_bounds__(256)
void k_gather(const u16* __restrict__ R, u16* __restrict__ out,
              const int* __restrict__ row_ptr, const int* __restrict__ csr_src,
              const float* __restrict__ stats, const float* __restrict__ g,
              const float* __restrict__ b) {
  const int wid = (blockIdx.x * 256 + threadIdx.x) >> 6;   // node
  if (wid >= NN) return;
  const int lane = threadIdx.x & 63;
  const int s = row_ptr[wid], e = row_ptr[wid + 1];
  const unsigned* R32 = (const unsigned*)R;
  float a0 = 0.f, a1 = 0.f;
  int i = s;
  for (; i + 7 < e; i += 8) {
    int q0 = csr_src[i],     q1 = csr_src[i + 1], q2 = csr_src[i + 2], q3 = csr_src[i + 3];
    int q4 = csr_src[i + 4], q5 = csr_src[i + 5], q6 = csr_src[i + 6], q7 = csr_src[i + 7];
    unsigned w0 = R32[(size_t)q0 * 64 + lane], w1 = R32[(size_t)q1 * 64 + lane];
    unsigned w2 = R32[(size_t)q2 * 64 + lane], w3 = R32[(size_t)q3 * 64 + lane];
    unsigned w4 = R32[(size_t)q4 * 64 + lane], w5 = R32[(size_t)q5 * 64 + lane];
    unsigned w6 = R32[(size_t)q6 * 64 + lane], w7 = R32[(size_t)q7 * 64 + lane];
    a0 += blo(w0) + blo(w1) + blo(w2) + blo(w3) + blo(w4) + blo(w5) + blo(w6) + blo(w7);
    a1 += bhi(w0) + bhi(w1) + bhi(w2) + bhi(w3) + bhi(w4) + bhi(w5) + bhi(w6) + bhi(w7);
  }
  for (; i < e; ++i) {
    unsigned v = R32[(size_t)csr_src[i] * 64 + lane];
    a0 += blo(v); a1 += bhi(v);
  }
  const int d0 = lane * 2;
  float dg = (float)(e - s);
  float m0 = stats[d0] * (1.f / NN), m1 = stats[d0 + 1] * (1.f / NN);
  float v0 = stats[DD + d0] * (1.f / NN) - m0 * m0;
  float v1 = stats[DD + d0 + 1] * (1.f / NN) - m1 * m1;
  float sc0 = g[d0] * rsqrtf(v0 + BN_EPS), sc1 = g[d0 + 1] * rsqrtf(v1 + BN_EPS);
  float sh0 = b[d0] - m0 * sc0, sh1 = b[d0 + 1] - m1 * sc1;
  float r0 = sc0 * a0 + sh0 * dg;
  float r1 = sc1 * a1 + sh1 * dg;
  unsigned pk = (unsigned)f2b(r0) | ((unsigned)f2b(r1) << 16);
  ((unsigned*)out)[(size_t)wid * 64 + lane] = pk;
}

// ---------------- weight prep ----------------
// MODE 1: in_stats/res_stats are RAW (NCOPY copies) — summed here.
template<int MODE>
__device__ __forceinline__ void wprep_body(
    const float* __restrict__ W, const float* __restrict__ bias,
    const float* __restrict__ in_stats, const float* __restrict__ in_g,
    const float* __restrict__ in_b,
    const float* __restrict__ res_stats, const float* __restrict__ res_g,
    const float* __restrict__ res_b,
    u16* __restrict__ WT, float* __restrict__ biasP, float* __restrict__ rese) {
  __shared__ float s_s[DD], s_t[DD];
  int t = threadIdx.x;
  if (t < DD) {
    float s = 1.f, tt = 0.f;
    if (MODE == 1) {
      float s1 = 0.f, s2 = 0.f, r1 = 0.f, r2 = 0.f;
#pragma unroll
      for (int i = 0; i < NCOPY; ++i) {
        s1 += in_stats[i * 256 + t];
        s2 += in_stats[i * 256 + DD + t];
        r1 += res_stats[i * 256 + t];
        r2 += res_stats[i * 256 + DD + t];
      }
      float mean = s1 * (1.f / NN);
      float var  = s2 * (1.f / NN) - mean * mean;
      float rs = rsqrtf(var + BN_EPS);
      s = in_g[t] * rs;
      tt = in_b[t] - mean * s;
      float m2 = r1 * (1.f / NN);
      float v2 = r2 * (1.f / NN) - m2 * m2;
      float rr = rsqrtf(v2 + BN_EPS);
      float sc = res_g[t] * rr;
      rese[t] = sc;
      rese[DD + t] = res_b[t] - m2 * sc;
    }
    s_s[t] = s; s_t[t] = tt;
  }
  __syncthreads();
  for (int idx = t; idx < DD * DD; idx += 256) {
    int k = idx >> 7, n = idx & 127;
    WT[n * DD + k] = f2b(W[idx] * s_s[k]);
  }
  if (t < DD) {
    float acc = bias[t];
    if (MODE == 1)
      for (int k = 0; k < DD; ++k) acc += s_t[k] * W[k * DD + t];
    biasP[t] = acc;
  }
}

__global__ void k_wprep0(const float* __restrict__ w_n2l_w, const float* __restrict__ w_n2l_b,
                         const float* __restrict__ conv_w, const float* __restrict__ conv_b,
                         u16* wt0, float* bp0, u16* wt1, float* bp1,
                         u16* wt3, float* bp3, u16* wt5, float* bp5) {
  int blk = blockIdx.x;
  const float* W; const float* bias; u16* WT; float* biasP;
  if (blk == 0)      { W = w_n2l_w;              bias = w_n2l_b;          WT = wt0; biasP = bp0; }
  else if (blk == 1) { W = conv_w;               bias = conv_b;           WT = wt1; biasP = bp1; }
  else if (blk == 2) { W = conv_w + DD * DD;     bias = conv_b + DD;      WT = wt3; biasP = bp3; }
  else               { W = conv_w + 2 * DD * DD; bias = conv_b + 2 * DD;  WT = wt5; biasP = bp5; }
  wprep_body<0>(W, bias, nullptr, nullptr, nullptr, nullptr, nullptr, nullptr,
                WT, biasP, nullptr);
}

__global__ void k_wprep1(const float* __restrict__ W, const float* __restrict__ bias,
                         const float* __restrict__ in_stats, const float* __restrict__ in_g,
                         const float* __restrict__ in_b,
                         const float* __restrict__ res_stats, const float* __restrict__ res_g,
                         const float* __restrict__ res_b,
                         u16* WT, float* biasP, float* rese) {
  wprep_body<1>(W, bias, in_stats, in_g, in_b, res_stats, res_g, res_b, WT, biasP, rese);
}

// swizzled LDS byte address: granule XOR within 8-granule (128B) halves of a 256B row
__device__ __forceinline__ int swz_addr(int row_bytes, int xr, int g, int o) {
  return row_bytes + ((((g & 7) ^ xr) | (g & 8)) << 4) + o;
}

// ---------------- MFMA GEMM, 128-row tiles, LDS-staged epilogue ----------------
// MODE 0: A bf16 (global_load_lds); e2n via K-extension MFMA from agg4/w_e2l
// MODE 1: A bf16 (global_load_lds); extra = affine(resid) staged via gload_lds->lds_a
// MODE 2: A fp32, on-the-fly bf16 cvt; e2n via K-extension MFMA
template<int MODE>
__global__ __launch_bounds__(256, 2)
void k_gemm(const void* __restrict__ Ain, const u16* __restrict__ WT,
            const float* __restrict__ biasP, u16* __restrict__ out,
            float* __restrict__ stats_out,
            const float* __restrict__ rese, const u16* __restrict__ resid,
            const float4* __restrict__ agg4,
            const float* __restrict__ w_e2l, const float* __restrict__ b_e2l) {
  __shared__ __align__(16) u16 lds_a[128 * 128];   // A (swz) -> resid (MODE1)
  __shared__ __align__(16) u16 lds_b[128 * 128];   // WT (swz) -> out staging
  __shared__ float sstats[256];
  const int tid  = threadIdx.x;
  const int lane = tid & 63;
  const int wv   = tid >> 6;
  const int row0 = blockIdx.x * 128;

  sstats[tid] = 0.f;

  // ---- stage WT and A ----
#pragma unroll
  for (int c = 0; c < 8; ++c) {
    int gidx = (wv * 8 + c) * 64 + lane;
    int row = gidx >> 4, gL = gidx & 15;
    int gS = (gL & 8) | ((gL & 7) ^ (row & 7));
    const u16* gsrcB = WT + (size_t)row * DD + gS * 8;
    u16* ldstB = lds_b + (size_t)(wv * 8 + c) * 512;
    __builtin_amdgcn_global_load_lds(
        (const __attribute__((address_space(1))) unsigned int*)gsrcB,
        (__attribute__((address_space(3))) unsigned int*)ldstB, 16, 0, 0);
    if (MODE != 2) {
      int arow = row0 + row; if (arow >= NN) arow = NN - 1;
      const u16* gsrcA = (const u16*)Ain + (size_t)arow * DD + gS * 8;
      u16* ldstA = lds_a + (size_t)(wv * 8 + c) * 512;
      __builtin_amdgcn_global_load_lds(
          (const __attribute__((address_space(1))) unsigned int*)gsrcA,
          (__attribute__((address_space(3))) unsigned int*)ldstA, 16, 0, 0);
    }
  }
  if (MODE == 2) {
    const float2* Af = (const float2*)Ain;       // row = 64 float2 (128 f32)
#pragma unroll
    for (int k = 0; k < 32; ++k) {
      int idx = k * 256 + tid;                   // 0..8191
      int r = idx >> 6, ln = idx & 63;
      int n = row0 + r; if (n >= NN) n = NN - 1;
      float2 v = Af[(size_t)n * 64 + ln];
      unsigned pk = (unsigned)f2b(v.x) | ((unsigned)f2b(v.y) << 16);
      int gLn = ln >> 2, oin = (ln & 3) * 4;
      int gS = (gLn & 8) | ((gLn & 7) ^ (r & 7));
      *(unsigned*)((char*)lds_a + r * 256 + gS * 16 + oin) = pk;
    }
  }
  __syncthreads();

  const int colid = lane & 15;
  const int lgrp  = lane >> 4;
  const int rowbase = wv * 32;
  const int o = (lgrp & 1) * 8;

  // ---- A fragments for this wave's 32 rows ----
  s16x8 afr[2][4];
#pragma unroll
  for (int rf = 0; rf < 2; ++rf) {
    int r = rowbase + rf * 16 + colid;
    int rb = r << 8, xr = r & 7;
#pragma unroll
    for (int ks = 0; ks < 4; ++ks) {
      int g0 = ks * 4 + (lgrp >> 1);
      uint2 lo = *(const uint2*)((const char*)lds_a + swz_addr(rb, xr, g0, o));
      uint2 hi = *(const uint2*)((const char*)lds_a + swz_addr(rb, xr, g0 + 2, o));
      union { unsigned u[4]; s16x8 v; } pk;
      pk.u[0] = lo.x; pk.u[1] = lo.y; pk.u[2] = hi.x; pk.u[3] = hi.y;
      afr[rf][ks] = pk.v;
    }
  }

  // ext A fragments: k=0..3 = agg4[row] on lgrp==0 lanes (MODE 0/2)
  s16x8 aext[2];
  if (MODE != 1) {
#pragma unroll
    for (int rf = 0; rf < 2; ++rf) {
      int r = row0 + rowbase + rf * 16 + colid;
      if (r >= NN) r = NN - 1;
      float4 a4 = agg4[r];
      union { unsigned u[4]; s16x8 v; } pk;
      pk.u[0] = (lgrp == 0) ? ((unsigned)f2b(a4.x) | ((unsigned)f2b(a4.y) << 16)) : 0u;
      pk.u[1] = (lgrp == 0) ? ((unsigned)f2b(a4.z) | ((unsigned)f2b(a4.w) << 16)) : 0u;
      pk.u[2] = 0u; pk.u[3] = 0u;
      aext[rf] = pk.v;
    }
  }
  __syncthreads();  // all waves done reading lds_a

  // ---- stage resid into lds_a (overlaps MFMA burst) ----
  if (MODE == 1) {
#pragma unroll
    for (int c = 0; c < 8; ++c) {
      int gidx = (wv * 8 + c) * 64 + lane;
      int row = gidx >> 4, gL = gidx & 15;
      int gS = (gL & 8) | ((gL & 7) ^ (row & 7));
      int arow = row0 + row; if (arow >= NN) arow = NN - 1;
      const u16* gsrcR = resid + (size_t)arow * DD + gS * 8;
      u16* ldstR = lds_a + (size_t)(wv * 8 + c) * 512;
      __builtin_amdgcn_global_load_lds(
          (const __attribute__((address_space(1))) unsigned int*)gsrcR,
          (__attribute__((address_space(3))) unsigned int*)ldstR, 16, 0, 0);
    }
  }

  // ---- compute: all 8 column-fragments in registers ----
  f32x4 acc[2][8];
#pragma unroll
  for (int cf = 0; cf < 8; ++cf) {
    const int col = cf * 16 + colid;
    const float bp = biasP[col];
    acc[0][cf] = (f32x4){bp, bp, bp, bp};
    acc[1][cf] = (f32x4){bp, bp, bp, bp};
    int nb = col << 8, xn = col & 7;
#pragma unroll
    for (int ks = 0; ks < 4; ++ks) {
      int g0 = ks * 4 + (lgrp >> 1);
      uint2 lo = *(const uint2*)((const char*)lds_b + swz_addr(nb, xn, g0, o));
      uint2 hi = *(const uint2*)((const char*)lds_b + swz_addr(nb, xn, g0 + 2, o));
      union { unsigned u[4]; s16x8 v; } pk;
      pk.u[0] = lo.x; pk.u[1] = lo.y; pk.u[2] = hi.x; pk.u[3] = hi.y;
      acc[0][cf] = __builtin_amdgcn_mfma_f32_16x16x32_bf16(afr[0][ks], pk.v, acc[0][cf], 0, 0, 0);
      acc[1][cf] = __builtin_amdgcn_mfma_f32_16x16x32_bf16(afr[1][ks], pk.v, acc[1][cf], 0, 0, 0);
    }
    if (MODE != 1) {
      // ext MFMA: + agg4 . [w_e2l rows; b_e2l]
      union { unsigned u[4]; s16x8 v; } bx;
      if (lgrp == 0) {
        float w0 = w_e2l[col], w1 = w_e2l[DD + col];
        float w2 = w_e2l[2 * DD + col], be = b_e2l[col];
        bx.u[0] = (unsigned)f2b(w0) | ((unsigned)f2b(w1) << 16);
        bx.u[1] = (unsigned)f2b(w2) | ((unsigned)f2b(be) << 16);
      } else { bx.u[0] = 0u; bx.u[1] = 0u; }
      bx.u[2] = 0u; bx.u[3] = 0u;
      acc[0][cf] = __builtin_amdgcn_mfma_f32_16x16x32_bf16(aext[0], bx.v, acc[0][cf], 0, 0, 0);
      acc[1][cf] = __builtin_amdgcn_mfma_f32_16x16x32_bf16(aext[1], bx.v, acc[1][cf], 0, 0, 0);
    }
  }
  __syncthreads();  // resid arrived (vmcnt drained by barrier); all B reads done

  // ---- epilogue: extra + relu + stats, staged into lds_b ----
#pragma unroll
  for (int cf = 0; cf < 8; ++cf) {
    const int col = cf * 16 + colid;
    float sc, sh;
    if (MODE == 1) { sc = rese[col]; sh = rese[DD + col]; }
    float s = 0.f, s2 = 0.f;
    int gc = col >> 3, cb = (col & 7) * 2;
#pragma unroll
    for (int rf = 0; rf < 2; ++rf)
#pragma unroll
      for (int q = 0; q < 4; ++q) {
        int rloc = rowbase + rf * 16 + lgrp * 4 + q;
        int r = row0 + rloc;
        float v = acc[rf][cf][q];
        if (MODE == 1) {
          int gsr = (gc & 8) | ((gc & 7) ^ (rloc & 7));
          u16 rv = *(const u16*)((const char*)lds_a + rloc * 256 + gsr * 16 + cb);
          v += sc * b2f(rv) + sh;
        }
        v = fmaxf(v, 0.f);
        if (r < NN) { s += v; s2 += v * v; }
        int gso = (gc & 8) | ((gc & 7) ^ (rloc & 7));
        *(u16*)((char*)lds_b + rloc * 256 + gso * 16 + cb) = f2b(v);
      }
    s  += __shfl_xor(s, 16);  s  += __shfl_xor(s, 32);
    s2 += __shfl_xor(s2, 16); s2 += __shfl_xor(s2, 32);
    if (lgrp == 0) {
      atomicAdd(&sstats[col], s);
      atomicAdd(&sstats[DD + col], s2);
    }
  }
  __syncthreads();

  // ---- coalesced store from lds_b ----
#pragma unroll
  for (int k = 0; k < 8; ++k) {
    int idx = k * 256 + tid;          // 0..2047
    int r = idx >> 4, g = idx & 15;
    if (row0 + r < NN) {
      int gd = (g & 8) | ((g & 7) ^ (r & 7));   // data granule stored at slot g
      uint4 v = *(const uint4*)((const char*)lds_b + r * 256 + g * 16);
      *(uint4*)(out + (size_t)(row0 + r) * DD + gd * 8) = v;
    }
  }
  atomicAdd(&stats_out[(blockIdx.x & (NCOPY - 1)) * 256 + tid], sstats[tid]);
}

// ---------------- segment max (bf16 input) ----------------
__global__ void k_segmax(const u16* __restrict__ R, const int* __restrict__ g_idx,
                         unsigned* __restrict__ gemb_enc,
                         const float* __restrict__ stats, const float* __restrict__ g,
                         const float* __restrict__ b) {
  int t = blockIdx.x * blockDim.x + threadIdx.x;
  int d = t & (DD - 1);
  int chunk = t >> 7;
  int n0 = chunk * 8;
  if (n0 >= NN) return;
  float mean = stats[d] * (1.f / NN);
  float var  = stats[DD + d] * (1.f / NN) - mean * mean;
  float rs = rsqrtf(var + BN_EPS);
  float scale = g[d] * rs;
  float shift = b[d] - mean * scale;
  int cur = -1; float run = 0.f;
  int nend = n0 + 8; if (nend > NN) nend = NN;
  for (int n = n0; n < nend; ++n) {
    float v = scale * b2f(R[(size_t)n * DD + d]) + shift;
    int gi = g_idx[n];
    if (gi != cur) {
      if (cur >= 0) atomicMax(&gemb_enc[cur * DD + d], enc_f(run));
      cur = gi; run = v;
    } else {
      run = fmaxf(run, v);
    }
  }
  if (cur >= 0) atomicMax(&gemb_enc[cur * DD + d], enc_f(run));
}

// ---------------- readout ----------------
__global__ void k_readout(const unsigned* __restrict__ gemb,
                          const float* __restrict__ W, const float* __restrict__ b,
                          float* __restrict__ out) {
  __shared__ float row[DD];
  int g = blockIdx.x, t = threadIdx.x;
  row[t] = dec_f(gemb[g * DD + t]);
  __syncthreads();
  float acc = b[t];
  for (int d = 0; d < DD; ++d) acc += row[d] * W[d * DD + t];
  out[g * DD + t] = fmaxf(acc, 0.f);
}

extern "C" void kernel_launch(void* const* d_in, const int* in_sizes, int n_in,
                              void* d_out, int out_size, void* d_ws, size_t ws_size,
                              hipStream_t stream) {
  const float* node_feat = (const float*)d_in[0];
  const float* edge_feat = (const float*)d_in[1];
  const int*   efrom     = (const int*)d_in[2];
  const int*   eto       = (const int*)d_in[3];
  const int*   g_idx     = (const int*)d_in[4];
  const float* w_n2l_w   = (const float*)d_in[6];
  const float* w_n2l_b   = (const float*)d_in[7];
  const float* w_e2l_w   = (const float*)d_in[8];   // [4][3][128]
  const float* w_e2l_b   = (const float*)d_in[9];   // [4][128]
  const float* conv_w    = (const float*)d_in[10];  // [3][128][128]
  const float* conv_b    = (const float*)d_in[11];
  const float* l2_w      = (const float*)d_in[12];
  const float* l2_b      = (const float*)d_in[13];
  const float* msg_bn_g  = (const float*)d_in[14];  // [4][128]
  const float* msg_bn_b  = (const float*)d_in[15];
  const float* hid_bn_g  = (const float*)d_in[16];  // [3][128]
  const float* hid_bn_b  = (const float*)d_in[17];
  const float* readout_w = (const float*)d_in[18];
  const float* readout_b = (const float*)d_in[19];
  float* out = (float*)d_out;
  (void)in_sizes; (void)n_in; (void)out_size; (void)ws_size;

  char* ws = (char*)d_ws;
  size_t off = 0;
  auto alloc = [&](size_t bytes) -> void* {
    void* p = ws + off; off += (bytes + 511) & ~(size_t)511; return p;
  };
  u16*      Pb0     = (u16*)alloc((size_t)NN * DD * 2);
  u16*      Pb1     = (u16*)alloc((size_t)NN * DD * 2);
  u16*      Pb2     = (u16*)alloc((size_t)NN * DD * 2);
  float*    agg4    = (float*)alloc((size_t)NN * 4 * 4);
  int*      cursor  = (int*)alloc((size_t)NN * 4);
  int*      row_ptr = (int*)alloc((size_t)(NN + 1) * 4);
  int*      tmp_pos = (int*)alloc((size_t)NE * 4);
  int*      csr_src = (int*)alloc((size_t)NE * 4);
  int*      csr_eid = (int*)alloc((size_t)NE * 4);
  int*      bsum    = (int*)alloc((size_t)NB * 4);
  int*      boff    = (int*)alloc((size_t)NB * 4);
  float*    stats   = (float*)alloc((size_t)7 * NCOPY * 256 * 4);  // raw copies
  float*    statfin = (float*)alloc((size_t)4 * 256 * 4);          // finalized msg stats
  unsigned* gemb    = (unsigned*)alloc((size_t)GG * DD * 4);
  u16*      wt[7];
  float*    bp[7];
  float*    re[7];
  for (int i = 0; i < 7; ++i) {
    wt[i] = (u16*)alloc((size_t)DD * DD * 2);
    bp[i] = (float*)alloc((size_t)DD * 4);
    re[i] = (float*)alloc((size_t)2 * DD * 4);
  }

  k_init<<<(NN + 255) / 256, 256, 0, stream>>>(cursor, stats, statfin, gemb);
  k_fill1<<<(NE + 255) / 256, 256, 0, stream>>>(eto, cursor, tmp_pos);
  k_scan1<<<NB, SCAN_B, 0, stream>>>(cursor, row_ptr, bsum);
  k_scan2<<<1, 128, 0, stream>>>(bsum, boff, row_ptr);
  k_scan3<<<(NN + 255) / 256, 256, 0, stream>>>(row_ptr, boff);
  k_fill2<<<(NE + 255) / 256, 256, 0, stream>>>(efrom, eto, tmp_pos, row_ptr,
                                                csr_src, csr_eid);
  k_node_ef<<<(NN * 16 + 255) / 256, 256, 0, stream>>>(edge_feat, row_ptr, csr_eid,
                                                       agg4);
  k_wprep0<<<4, 256, 0, stream>>>(w_n2l_w, w_n2l_b, conv_w, conv_b,
                                  wt[0], bp[0], wt[1], bp[1], wt[3], bp[3], wt[5], bp[5]);

  // raw stat buffers: [msg0..msg3, hid0..hid2] x (NCOPY*256)
  float* msg_raw[4] = { stats + 0*NCOPY*256, stats + 1*NCOPY*256,
                        stats + 2*NCOPY*256, stats + 3*NCOPY*256 };
  float* hid_raw[3] = { stats + 4*NCOPY*256, stats + 5*NCOPY*256, stats + 6*NCOPY*256 };
  float* msg_fin[4] = { statfin, statfin + 256, statfin + 512, statfin + 768 };
  const int GEMM_GRID = (NN + 127) / 128;  // 782

  // GEMM0 (MODE 2): Pb0 = relu(bf16(node_feat) @ w_n2l + b + e2n0); raw stats -> msg0
  k_gemm<2><<<GEMM_GRID, 256, 0, stream>>>(node_feat, wt[0], bp[0], Pb0, msg_raw[0],
      nullptr, nullptr, (const float4*)agg4, w_e2l_w + 0 * 3 * DD, w_e2l_b + 0 * DD);
  k_redstat<<<1, 256, 0, stream>>>(msg_raw[0], msg_fin[0]);

  u16* R = Pb0; u16* other = Pb1;
  for (int lv = 0; lv < 3; ++lv) {
    int wc = 1 + 2 * lv, wl = 2 + 2 * lv;
    // agg = affine_msg[lv](seg(R[from])) -> other
    k_gather<<<(NN * 64 + 255) / 256, 256, 0, stream>>>(R, other, row_ptr, csr_src,
        msg_fin[lv], msg_bn_g + lv * DD, msg_bn_b + lv * DD);
    // conv (MODE 0): Pb2 = relu(other @ conv_w[lv] + conv_b + e2n[lv+1]); raw -> hid[lv]
    k_gemm<0><<<GEMM_GRID, 256, 0, stream>>>(other, wt[wc], bp[wc], Pb2, hid_raw[lv],
        nullptr, nullptr, (const float4*)agg4,
        w_e2l_w + (size_t)(lv + 1) * 3 * DD, w_e2l_b + (lv + 1) * DD);
    // l2 (MODE 1): other = relu(norm_hid(Pb2) @ l2_w[lv] + l2_b + affine_msg[lv](R))
    k_wprep1<<<1, 256, 0, stream>>>(l2_w + (size_t)lv * DD * DD, l2_b + lv * DD,
        hid_raw[lv], hid_bn_g + lv * DD, hid_bn_b + lv * DD,
        msg_raw[lv], msg_bn_g + lv * DD, msg_bn_b + lv * DD, wt[wl], bp[wl], re[wl]);
    k_gemm<1><<<GEMM_GRID, 256, 0, stream>>>(Pb2, wt[wl], bp[wl], other, msg_raw[lv + 1],
        re[wl], R, nullptr, nullptr, nullptr);
    k_redstat<<<1, 256, 0, stream>>>(msg_raw[lv + 1], msg_fin[lv + 1]);
    u16* t = R; R = other; other = t;
  }

  k_segmax<<<(NN / 8) * DD / 256, 256, 0, stream>>>(
      R, g_idx, gemb, msg_fin[3], msg_bn_g + 3 * DD, msg_bn_b + 3 * DD);
  k_readout<<<GG, DD, 0, stream>>>(gemb, readout_w, readout_b, out);
}